// Round 10
// baseline (955.350 us; speedup 1.0000x reference)
//
#include <hip/hip_runtime.h>

#define NN 50000
#define NE 800000

typedef __attribute__((ext_vector_type(8))) short bf16x8;
typedef __attribute__((ext_vector_type(4))) float f32x4;

__device__ __forceinline__ ushort f2bf(float x) {
    union { float f; unsigned u; } v; v.f = x;
    return (ushort)((v.u + 0x7FFF + ((v.u >> 16) & 1)) >> 16);
}
__device__ __forceinline__ float bf2f(ushort b) {
    union { float f; unsigned u; } v; v.u = ((unsigned)b) << 16;
    return v.f;
}

// ================= CSR build: hist / inv / scan / scatter =================
__global__ void hist_kernel(const int* __restrict__ recv, int* __restrict__ cnt) {
    int i = blockIdx.x * 256 + threadIdx.x;
    if (i < NE) atomicAdd(&cnt[recv[i]], 1);
}

__global__ void inv_kernel(const int* __restrict__ cnt, float* __restrict__ inv) {
    int i = blockIdx.x * 256 + threadIdx.x;
    if (i < NN) inv[i] = 1.0f / (float)max(cnt[i], 1);
}

__global__ void scan1_kernel(const int* __restrict__ cnt, int* __restrict__ excl,
                             int* __restrict__ bsum) {
    const int i = blockIdx.x * 256 + threadIdx.x;
    const int lane = threadIdx.x & 63, wid = threadIdx.x >> 6;
    int orig = (i < NN) ? cnt[i] : 0;
    int x = orig;
    #pragma unroll
    for (int off = 1; off < 64; off <<= 1) {
        int y = __shfl_up(x, off, 64);
        if (lane >= off) x += y;
    }
    __shared__ int ws[4];
    if (lane == 63) ws[wid] = x;
    __syncthreads();
    int add = 0;
    for (int w = 0; w < wid; ++w) add += ws[w];
    x += add;
    if (i < NN) excl[i] = x - orig;
    if (threadIdx.x == 255) bsum[blockIdx.x] = x;
}

__global__ void scan2_kernel(int* __restrict__ bsum, int nb) {
    const int t = threadIdx.x;
    const int lane = t & 63, wid = t >> 6;
    int orig = (t < nb) ? bsum[t] : 0;
    int x = orig;
    #pragma unroll
    for (int off = 1; off < 64; off <<= 1) {
        int y = __shfl_up(x, off, 64);
        if (lane >= off) x += y;
    }
    __shared__ int ws[4];
    if (lane == 63) ws[wid] = x;
    __syncthreads();
    int add = 0;
    for (int w = 0; w < wid; ++w) add += ws[w];
    x += add;
    __syncthreads();
    if (t < nb) bsum[t] = x - orig;
}

__global__ void scan3_kernel(int* __restrict__ excl, const int* __restrict__ bsum) {
    const int i = blockIdx.x * 256 + threadIdx.x;
    if (i < NN) excl[i] += bsum[blockIdx.x];
    if (i == 0) excl[NN] = NE;
}

__global__ void scatter_kernel(const int* __restrict__ senders, const int* __restrict__ recv,
                               const int* __restrict__ row_start,
                               int* __restrict__ cursor, int* __restrict__ eidx,
                               int* __restrict__ sid, int* __restrict__ rid) {
    int i = blockIdx.x * 256 + threadIdx.x;
    if (i < NE) {
        int r = recv[i];
        int p = row_start[r] + atomicAdd(&cursor[r], 1);
        eidx[p] = i;
        sid[p] = senders[i];
        rid[p] = r;
    }
}

// ============ fused P|Q GEMM: [P|Q] = A @ [Wp|Wq], one A pass =============
__launch_bounds__(256, 3)
__global__ void gemm_pq_kernel(const float* __restrict__ A, int M,
                               const float* __restrict__ Wp_,  // [64][64]
                               const float* __restrict__ Wq_,  // [64][64]
                               float* __restrict__ Pout, float* __restrict__ Qout) {
    __shared__ float w_lds[64 * 128];
    __shared__ float e_lds[64 * 68];
    const int tid = threadIdx.x;
    for (int i = tid; i < 8192; i += 256) {
        const int k = i >> 7, c = i & 127;
        w_lds[i] = (c < 64) ? Wp_[k * 64 + c] : Wq_[k * 64 + (c - 64)];
    }
    const int te = tid & 15;
    const int tc = tid >> 4;
    const int srow = tid >> 2, shalf = tid & 3;
    const int ntiles = (M + 63) >> 6;

    for (int t = blockIdx.x; t < ntiles; t += gridDim.x) {
        const int base = t << 6;
        __syncthreads();
        {
            int g = base + srow;
            if (g > M - 1) g = M - 1;
            const float4* src = (const float4*)(A + (size_t)g * 64) + shalf * 4;
            float4* dst = (float4*)&e_lds[srow * 68 + shalf * 16];
            #pragma unroll
            for (int j = 0; j < 4; ++j) dst[j] = src[j];
        }
        __syncthreads();

        float4 acc0[4], acc1[4];
        #pragma unroll
        for (int i = 0; i < 4; ++i) {
            acc0[i] = make_float4(0.f, 0.f, 0.f, 0.f);
            acc1[i] = make_float4(0.f, 0.f, 0.f, 0.f);
        }

        #pragma unroll 2
        for (int kq = 0; kq < 16; ++kq) {
            float evs[4][4];
            #pragma unroll
            for (int i = 0; i < 4; ++i) {
                const float4 q = *(const float4*)&e_lds[(te + 16 * i) * 68 + kq * 4];
                evs[i][0] = q.x; evs[i][1] = q.y; evs[i][2] = q.z; evs[i][3] = q.w;
            }
            #pragma unroll
            for (int j = 0; j < 4; ++j) {
                const float4 w0 = *(const float4*)&w_lds[(kq * 4 + j) * 128 + tc * 8];
                const float4 w1 = *(const float4*)&w_lds[(kq * 4 + j) * 128 + tc * 8 + 4];
                #pragma unroll
                for (int i = 0; i < 4; ++i) {
                    const float ev = evs[i][j];
                    acc0[i].x = fmaf(ev, w0.x, acc0[i].x);
                    acc0[i].y = fmaf(ev, w0.y, acc0[i].y);
                    acc0[i].z = fmaf(ev, w0.z, acc0[i].z);
                    acc0[i].w = fmaf(ev, w0.w, acc0[i].w);
                    acc1[i].x = fmaf(ev, w1.x, acc1[i].x);
                    acc1[i].y = fmaf(ev, w1.y, acc1[i].y);
                    acc1[i].z = fmaf(ev, w1.z, acc1[i].z);
                    acc1[i].w = fmaf(ev, w1.w, acc1[i].w);
                }
            }
        }

        float* __restrict__ dstbuf = (tc < 8) ? Pout : Qout;
        const int cd = (tc < 8) ? tc * 8 : (tc - 8) * 8;
        #pragma unroll
        for (int i = 0; i < 4; ++i) {
            const int g = base + te + 16 * i;
            if (g < M) {
                *(float4*)(dstbuf + (size_t)g * 64 + cd) = acc0[i];
                *(float4*)(dstbuf + (size_t)g * 64 + cd + 4) = acc1[i];
            }
        }
    }
}

// ============ CSR-fused edge GEMM (split-bf16 MFMA) + segment-sum =========
// A@W via mfma_f32_16x16x32_bf16 with a = ah+al, w = wh+wl (3-term split:
// ah*wh + ah*wl + al*wh -> ~1e-5 rel accuracy). W lives in REGISTERS as
// B-fragments (no LDS reads for W); A staged in LDS as two bf16 tiles
// (hi/lo), one ds_read_b128 per A-fragment. Skeleton (staging barrier ->
// in-place safety; epilogue; segsum) is round-7's, epilogue re-indexed for
// the MFMA C layout: col=lane&15, row=(lane>>4)*4+reg  [m89-verified].
__launch_bounds__(256, 3)
__global__ void edge_csr_kernel(const float* A,
                                const int* __restrict__ gidx,   // eidx (l==0) or null
                                const float* __restrict__ W,    // [64][64]
                                const float* __restrict__ bias, // [64]
                                const float* __restrict__ P,
                                const float* __restrict__ Q,
                                const int* __restrict__ sid,
                                const int* __restrict__ rid,
                                const int* __restrict__ row_start,
                                float* out,
                                float* __restrict__ agg) {
    // LDS: phase A = a_hi[128][72] + a_lo[128][72] (bf16, 36.9 KB total);
    //      phase B = stash fp32 [128][68] (34.8 KB) aliased over the same
    //      memory. Barriers separate all uses.
    __shared__ ushort smem[2 * 128 * 72];
    ushort* a_hi = smem;
    ushort* a_lo = smem + 128 * 72;
    float*  stash = (float*)smem;

    const int tid  = threadIdx.x;
    const int lane = tid & 63;
    const int wid  = tid >> 6;

    // ---- W -> register B-fragments (hi/lo bf16). Lane holds col=lane&15,
    //      k = 32*kt + (lane>>4)*8 + j.
    const int colB  = lane & 15;
    const int krowB = (lane >> 4) * 8;
    bf16x8 wh[2][4], wl[2][4];
    #pragma unroll
    for (int kt = 0; kt < 2; ++kt)
        #pragma unroll
        for (int nt = 0; nt < 4; ++nt) {
            #pragma unroll
            for (int j = 0; j < 8; ++j) {
                const float w = W[(32 * kt + krowB + j) * 64 + (16 * nt + colB)];
                const ushort h = f2bf(w);
                wh[kt][nt][j] = (short)h;
                wl[kt][nt][j] = (short)f2bf(w - bf2f(h));
            }
        }
    // bias per lane: c = 16*nt + (lane&15)
    float bv[4];
    #pragma unroll
    for (int nt = 0; nt < 4; ++nt) bv[nt] = bias[16 * nt + colB];

    const int srow = tid >> 1, shalf = tid & 1;   // staging: row, col-half
    const int rowA = lane & 15;                   // A-frag row within group
    const int kgA  = lane >> 4;                   // A-frag k-subgroup
    const int rowC = (lane >> 4) * 4;             // C-frag row base
    const int colC = lane & 15;                   // C-frag col

    for (int t = blockIdx.x; t < NE / 128; t += gridDim.x) {
        const int base = t << 7;
        __syncthreads();   // prev iter's segsum reads of stash complete
        {   // stage A rows as bf16 hi/lo (reads before any aliased write)
            const int g = base + srow;
            const int src = gidx ? gidx[g] : g;
            const float4* s4 = (const float4*)(A + (size_t)src * 64) + shalf * 8;
            ushort* dh = &a_hi[srow * 72 + shalf * 32];
            ushort* dl = &a_lo[srow * 72 + shalf * 32];
            #pragma unroll
            for (int jj = 0; jj < 8; ++jj) {
                const float4 v = s4[jj];
                const ushort h0 = f2bf(v.x), h1 = f2bf(v.y), h2 = f2bf(v.z), h3 = f2bf(v.w);
                const ushort l0 = f2bf(v.x - bf2f(h0)), l1 = f2bf(v.y - bf2f(h1));
                const ushort l2 = f2bf(v.z - bf2f(h2)), l3 = f2bf(v.w - bf2f(h3));
                uint2 ph, pl;
                ph.x = (unsigned)h0 | ((unsigned)h1 << 16);
                ph.y = (unsigned)h2 | ((unsigned)h3 << 16);
                pl.x = (unsigned)l0 | ((unsigned)l1 << 16);
                pl.y = (unsigned)l2 | ((unsigned)l3 << 16);
                *(uint2*)&dh[jj * 4] = ph;
                *(uint2*)&dl[jj * 4] = pl;
            }
        }
        __syncthreads();   // tile fully staged; all A reads done -> in-place safe

        // ---- MFMA: wave wid handles row-groups 2*wid, 2*wid+1 ----
        f32x4 acc[2][4];
        #pragma unroll
        for (int gg = 0; gg < 2; ++gg)
            #pragma unroll
            for (int nt = 0; nt < 4; ++nt) acc[gg][nt] = (f32x4)0.0f;

        #pragma unroll
        for (int gg = 0; gg < 2; ++gg) {
            const int row = (wid * 2 + gg) * 16 + rowA;
            const ushort* ap = &a_hi[row * 72];
            #pragma unroll
            for (int kt = 0; kt < 2; ++kt) {
                const bf16x8 ah = *(const bf16x8*)&ap[kt * 32 + kgA * 8];
                const bf16x8 al = *(const bf16x8*)&ap[128 * 72 + kt * 32 + kgA * 8];
                #pragma unroll
                for (int nt = 0; nt < 4; ++nt) {
                    acc[gg][nt] = __builtin_amdgcn_mfma_f32_16x16x32_bf16(
                        ah, wh[kt][nt], acc[gg][nt], 0, 0, 0);
                    acc[gg][nt] = __builtin_amdgcn_mfma_f32_16x16x32_bf16(
                        ah, wl[kt][nt], acc[gg][nt], 0, 0, 0);
                    acc[gg][nt] = __builtin_amdgcn_mfma_f32_16x16x32_bf16(
                        al, wh[kt][nt], acc[gg][nt], 0, 0, 0);
                }
            }
        }
        __syncthreads();   // all MFMA LDS reads done -> stash may overwrite

        // ---- epilogue in C-fragment layout ----
        #pragma unroll
        for (int gg = 0; gg < 2; ++gg) {
            #pragma unroll
            for (int j = 0; j < 4; ++j) {
                const int row = (wid * 2 + gg) * 16 + rowC + j;
                const int e = base + row;
                const int s = sid[e];
                const int r = rid[e];
                #pragma unroll
                for (int nt = 0; nt < 4; ++nt) {
                    const int c = 16 * nt + colC;
                    float o = acc[gg][nt][j] + bv[nt]
                            + P[(size_t)s * 64 + c] + Q[(size_t)r * 64 + c];
                    o = fmaxf(o, 0.f);
                    out[(size_t)e * 64 + c] = o;
                    stash[row * 68 + c] = o;
                }
            }
        }
        __syncthreads();   // output tile fully in stash

        // ---- segment-sum over this tile's receiver range ----
        const int v0 = rid[base];
        const int v1 = rid[base + 127];
        const int nv = v1 - v0 + 1;
        for (int idx = tid; idx < nv * 16; idx += 256) {
            const int v  = v0 + (idx >> 4);
            const int cg = (idx & 15) * 4;
            int lo = row_start[v], hi = row_start[v + 1];
            lo = lo > base ? lo : base;
            hi = hi < base + 128 ? hi : base + 128;
            if (lo < hi) {
                float4 sum = make_float4(0.f, 0.f, 0.f, 0.f);
                for (int j = lo - base; j < hi - base; ++j) {
                    const float4 ev = *(const float4*)&stash[j * 68 + cg];
                    sum.x += ev.x; sum.y += ev.y; sum.z += ev.z; sum.w += ev.w;
                }
                float* ap = agg + (size_t)v * 64 + cg;
                atomicAdd(ap + 0, sum.x);
                atomicAdd(ap + 1, sum.y);
                atomicAdd(ap + 2, sum.z);
                atomicAdd(ap + 3, sum.w);
            }
        }
    }
}

// ====== node update: relu([nodes | agg*inv] @ Wn + bn), K=128 =============
__launch_bounds__(256, 3)
__global__ void node_kernel(const float* __restrict__ nodes_in,
                            const float* __restrict__ agg,   // raw sums
                            const float* __restrict__ inv,   // 1/max(count,1)
                            const float* __restrict__ W,     // [128][64]
                            const float* __restrict__ bias,  // [64]
                            float* __restrict__ out) {
    __shared__ float w_lds[128 * 64];
    __shared__ float e_lds[128 * 33];
    const int tid = threadIdx.x;
    for (int i = tid; i < 8192; i += 256) w_lds[i] = W[i];
    const int te = tid & 15, tc = tid >> 4, c0 = tc * 4;
    const float4 bv = *(const float4*)(bias + c0);
    const int srow = tid >> 1, shalf = tid & 1;
    const int ntiles = (NN + 127) >> 7;

    for (int t = blockIdx.x; t < ntiles; t += gridDim.x) {
        const int base = t << 7;
        float4 acc[8];
        #pragma unroll
        for (int i = 0; i < 8; ++i) acc[i] = make_float4(0.f, 0.f, 0.f, 0.f);

        #pragma unroll
        for (int c = 0; c < 4; ++c) {
            const float* src0 = (c < 2) ? nodes_in : agg;
            const int coff = (c & 1) * 32;
            __syncthreads();
            {
                int g = base + srow;
                if (g > NN - 1) g = NN - 1;
                const float4* src = (const float4*)(src0 + (size_t)g * 64 + coff) + shalf * 4;
                const float scale = (c >= 2) ? inv[g] : 1.0f;
                float* dst = &e_lds[srow * 33 + shalf * 16];
                #pragma unroll
                for (int j = 0; j < 4; ++j) {
                    float4 v = src[j];
                    dst[j * 4 + 0] = v.x * scale; dst[j * 4 + 1] = v.y * scale;
                    dst[j * 4 + 2] = v.z * scale; dst[j * 4 + 3] = v.w * scale;
                }
            }
            __syncthreads();
            #pragma unroll 4
            for (int k = 0; k < 32; ++k) {
                const float4 wv = *(const float4*)&w_lds[(c * 32 + k) * 64 + c0];
                #pragma unroll
                for (int i = 0; i < 8; ++i) {
                    const float ev = e_lds[(te + 16 * i) * 33 + k];
                    acc[i].x = fmaf(ev, wv.x, acc[i].x);
                    acc[i].y = fmaf(ev, wv.y, acc[i].y);
                    acc[i].z = fmaf(ev, wv.z, acc[i].z);
                    acc[i].w = fmaf(ev, wv.w, acc[i].w);
                }
            }
        }

        #pragma unroll
        for (int i = 0; i < 8; ++i) {
            const int v = base + te + 16 * i;
            if (v < NN) {
                float4 o = acc[i];
                o.x = fmaxf(o.x + bv.x, 0.f); o.y = fmaxf(o.y + bv.y, 0.f);
                o.z = fmaxf(o.z + bv.z, 0.f); o.w = fmaxf(o.w + bv.w, 0.f);
                *(float4*)(out + (size_t)v * 64 + c0) = o;
            }
        }
    }
}

// ================= final: LN + MLP + projection (LDS-broadcast GEMMs) =====
__launch_bounds__(256, 2)
__global__ void final_kernel(const float* __restrict__ nodes,
                             const float* __restrict__ gamma,
                             const float* __restrict__ beta,
                             const float* __restrict__ W1, const float* __restrict__ b1,
                             const float* __restrict__ W2, const float* __restrict__ b2,
                             const float* __restrict__ Wp, const float* __restrict__ bp,
                             float* __restrict__ out) {
    __shared__ float w1_lds[64 * 128];
    __shared__ float w2_lds[128 * 64];
    __shared__ float x_lds[16 * 66];
    __shared__ float h_lds[16 * 130];
    const int tid = threadIdx.x;
    for (int i = tid; i < 8192; i += 256) w1_lds[i] = W1[i];
    for (int i = tid; i < 8192; i += 256) w2_lds[i] = W2[i];
    const int r  = tid >> 4;
    const int li = tid & 15;
    const float4 gm4 = *(const float4*)(gamma + li * 4);
    const float4 bt4 = *(const float4*)(beta + li * 4);
    const float4 b1v0 = *(const float4*)(b1 + li * 8);
    const float4 b1v1 = *(const float4*)(b1 + li * 8 + 4);
    const float4 b2v = *(const float4*)(b2 + li * 4);
    const float4 wpv = *(const float4*)(Wp + li * 4);
    const float bp0 = bp[0];

    for (int tile = blockIdx.x; tile < NN / 16; tile += gridDim.x) {
        const int vbase = tile * 16;
        const float4 xv = *(const float4*)(nodes + (size_t)(vbase + r) * 64 + li * 4);
        float s = xv.x + xv.y + xv.z + xv.w;
        #pragma unroll
        for (int off = 1; off < 16; off <<= 1) s += __shfl_xor(s, off, 16);
        const float mu = s * (1.0f / 64.0f);
        const float dx = xv.x - mu, dy = xv.y - mu, dz = xv.z - mu, dw = xv.w - mu;
        float q = dx * dx + dy * dy + dz * dz + dw * dw;
        #pragma unroll
        for (int off = 1; off < 16; off <<= 1) q += __shfl_xor(q, off, 16);
        const float rs = rsqrtf(q * (1.0f / 64.0f) + 1e-5f);
        float* xp = &x_lds[r * 66 + li * 4];
        xp[0] = dx * rs * gm4.x + bt4.x;
        xp[1] = dy * rs * gm4.y + bt4.y;
        xp[2] = dz * rs * gm4.z + bt4.z;
        xp[3] = dw * rs * gm4.w + bt4.w;
        __syncthreads();

        float4 h0 = make_float4(0.f, 0.f, 0.f, 0.f);
        float4 h1 = make_float4(0.f, 0.f, 0.f, 0.f);
        #pragma unroll 8
        for (int k = 0; k < 64; ++k) {
            const float xk = x_lds[r * 66 + k];
            const float4 w0 = *(const float4*)&w1_lds[k * 128 + li * 8];
            const float4 w1v = *(const float4*)&w1_lds[k * 128 + li * 8 + 4];
            h0.x = fmaf(xk, w0.x, h0.x); h0.y = fmaf(xk, w0.y, h0.y);
            h0.z = fmaf(xk, w0.z, h0.z); h0.w = fmaf(xk, w0.w, h0.w);
            h1.x = fmaf(xk, w1v.x, h1.x); h1.y = fmaf(xk, w1v.y, h1.y);
            h1.z = fmaf(xk, w1v.z, h1.z); h1.w = fmaf(xk, w1v.w, h1.w);
        }
        float* hp = &h_lds[r * 130 + li * 8];
        hp[0] = fmaxf(h0.x + b1v0.x, 0.f);
        hp[1] = fmaxf(h0.y + b1v0.y, 0.f);
        hp[2] = fmaxf(h0.z + b1v0.z, 0.f);
        hp[3] = fmaxf(h0.w + b1v0.w, 0.f);
        hp[4] = fmaxf(h1.x + b1v1.x, 0.f);
        hp[5] = fmaxf(h1.y + b1v1.y, 0.f);
        hp[6] = fmaxf(h1.z + b1v1.z, 0.f);
        hp[7] = fmaxf(h1.w + b1v1.w, 0.f);
        __syncthreads();

        float4 o = make_float4(0.f, 0.f, 0.f, 0.f);
        #pragma unroll 8
        for (int k = 0; k < 128; ++k) {
            const float hk = h_lds[r * 130 + k];
            const float4 w = *(const float4*)&w2_lds[k * 64 + li * 4];
            o.x = fmaf(hk, w.x, o.x); o.y = fmaf(hk, w.y, o.y);
            o.z = fmaf(hk, w.z, o.z); o.w = fmaf(hk, w.w, o.w);
        }
        float p = (o.x + b2v.x) * wpv.x + (o.y + b2v.y) * wpv.y +
                  (o.z + b2v.z) * wpv.z + (o.w + b2v.w) * wpv.w;
        #pragma unroll
        for (int off = 1; off < 16; off <<= 1) p += __shfl_xor(p, off, 16);
        if (li == 0) out[vbase + r] = p + bp0;
    }
}

extern "C" void kernel_launch(void* const* d_in, const int* in_sizes, int n_in,
                              void* d_out, int out_size, void* d_ws, size_t ws_size,
                              hipStream_t stream) {
    const float* nodes     = (const float*)d_in[0];
    const float* edges     = (const float*)d_in[1];
    const int*   senders   = (const int*)d_in[2];
    const int*   receivers = (const int*)d_in[3];
    const float* We        = (const float*)d_in[4];
    const float* be        = (const float*)d_in[5];
    const float* Wn        = (const float*)d_in[6];
    const float* bn        = (const float*)d_in[7];
    const float* gamma     = (const float*)d_in[8];
    const float* beta      = (const float*)d_in[9];
    const float* W1        = (const float*)d_in[10];
    const float* b1        = (const float*)d_in[11];
    const float* W2        = (const float*)d_in[12];
    const float* b2        = (const float*)d_in[13];
    const float* Wp        = (const float*)d_in[14];
    const float* bp        = (const float*)d_in[15];
    float* out = (float*)d_out;

    float* ws        = (float*)d_ws;
    float* edges_buf = ws;                                   // [NE][64]  204.8 MB (CSR order)
    float* Pbuf      = edges_buf + (size_t)NE * 64;          // [NN][64]
    float* Qbuf      = Pbuf + (size_t)NN * 64;               // [NN][64]
    float* nodes_buf = Qbuf + (size_t)NN * 64;               // [NN][64]
    float* aggbuf    = nodes_buf + (size_t)NN * 64;          // [NN][64] raw sums
    int*   cnt_i     = (int*)(aggbuf + (size_t)NN * 64);     // [NN]
    int*   row_start = cnt_i + NN;                           // [NN+1]
    int*   cursor    = row_start + NN + 1;                   // [NN]
    int*   eidx      = cursor + NN;                          // [NE]
    int*   sid       = eidx + NE;                            // [NE]
    int*   rid       = sid + NE;                             // [NE]
    int*   bsum      = rid + NE;                             // [256]
    float* inv       = (float*)(bsum + 256);                 // [NN]

    hipMemsetAsync(cnt_i, 0, NN * sizeof(int), stream);
    hipMemsetAsync(cursor, 0, NN * sizeof(int), stream);
    hist_kernel<<<(NE + 255) / 256, 256, 0, stream>>>(receivers, cnt_i);
    inv_kernel<<<(NN + 255) / 256, 256, 0, stream>>>(cnt_i, inv);
    scan1_kernel<<<196, 256, 0, stream>>>(cnt_i, row_start, bsum);
    scan2_kernel<<<1, 256, 0, stream>>>(bsum, 196);
    scan3_kernel<<<196, 256, 0, stream>>>(row_start, bsum);
    scatter_kernel<<<(NE + 255) / 256, 256, 0, stream>>>(senders, receivers, row_start,
                                                         cursor, eidx, sid, rid);

    for (int l = 0; l < 3; ++l) {
        const float* ncur = (l == 0) ? nodes : nodes_buf;
        const float* We_l = We + (size_t)l * 192 * 64;
        // [P|Q] = nodes @ [We[64:128] | We[128:192]]  (one A pass)
        gemm_pq_kernel<<<782, 256, 0, stream>>>(ncur, NN, We_l + 64 * 64, We_l + 128 * 64,
                                                Pbuf, Qbuf);
        // zero agg sums, then fused edge GEMM (split-bf16 MFMA) + aggregation
        hipMemsetAsync(aggbuf, 0, (size_t)NN * 64 * sizeof(float), stream);
        edge_csr_kernel<<<3125, 256, 0, stream>>>(
            (l == 0) ? edges : edges_buf,
            (l == 0) ? eidx : (const int*)nullptr,
            We_l, be + (size_t)l * 64, Pbuf, Qbuf,
            sid, rid, row_start, edges_buf, aggbuf);
        // nodes = relu([nodes | agg*inv] @ Wn + bn)
        node_kernel<<<391, 256, 0, stream>>>(ncur, aggbuf, inv,
                                             Wn + (size_t)l * 128 * 64, bn + (size_t)l * 64,
                                             nodes_buf);
    }
    final_kernel<<<625, 256, 0, stream>>>(nodes_buf, gamma, beta,
                                          W1, b1, W2, b2, Wp, bp, out);
}

// Round 11
// 789.741 us; speedup vs baseline: 1.2097x; 1.2097x over previous
//
#include <hip/hip_runtime.h>

#define NN 50000
#define NE 800000

// ================= CSR build: hist / inv / scan / scatter =================
__global__ void hist_kernel(const int* __restrict__ recv, int* __restrict__ cnt) {
    int i = blockIdx.x * 256 + threadIdx.x;
    if (i < NE) atomicAdd(&cnt[recv[i]], 1);
}

__global__ void inv_kernel(const int* __restrict__ cnt, float* __restrict__ inv) {
    int i = blockIdx.x * 256 + threadIdx.x;
    if (i < NN) inv[i] = 1.0f / (float)max(cnt[i], 1);
}

__global__ void scan1_kernel(const int* __restrict__ cnt, int* __restrict__ excl,
                             int* __restrict__ bsum) {
    const int i = blockIdx.x * 256 + threadIdx.x;
    const int lane = threadIdx.x & 63, wid = threadIdx.x >> 6;
    int orig = (i < NN) ? cnt[i] : 0;
    int x = orig;
    #pragma unroll
    for (int off = 1; off < 64; off <<= 1) {
        int y = __shfl_up(x, off, 64);
        if (lane >= off) x += y;
    }
    __shared__ int ws[4];
    if (lane == 63) ws[wid] = x;
    __syncthreads();
    int add = 0;
    for (int w = 0; w < wid; ++w) add += ws[w];
    x += add;
    if (i < NN) excl[i] = x - orig;
    if (threadIdx.x == 255) bsum[blockIdx.x] = x;
}

__global__ void scan2_kernel(int* __restrict__ bsum, int nb) {
    const int t = threadIdx.x;
    const int lane = t & 63, wid = t >> 6;
    int orig = (t < nb) ? bsum[t] : 0;
    int x = orig;
    #pragma unroll
    for (int off = 1; off < 64; off <<= 1) {
        int y = __shfl_up(x, off, 64);
        if (lane >= off) x += y;
    }
    __shared__ int ws[4];
    if (lane == 63) ws[wid] = x;
    __syncthreads();
    int add = 0;
    for (int w = 0; w < wid; ++w) add += ws[w];
    x += add;
    __syncthreads();
    if (t < nb) bsum[t] = x - orig;
}

__global__ void scan3_kernel(int* __restrict__ excl, const int* __restrict__ bsum) {
    const int i = blockIdx.x * 256 + threadIdx.x;
    if (i < NN) excl[i] += bsum[blockIdx.x];
    if (i == 0) excl[NN] = NE;
}

__global__ void scatter_kernel(const int* __restrict__ senders, const int* __restrict__ recv,
                               const int* __restrict__ row_start,
                               int* __restrict__ cursor, int* __restrict__ eidx,
                               int* __restrict__ sid, int* __restrict__ rid) {
    int i = blockIdx.x * 256 + threadIdx.x;
    if (i < NE) {
        int r = recv[i];
        int p = row_start[r] + atomicAdd(&cursor[r], 1);
        eidx[p] = i;
        sid[p] = senders[i];
        rid[p] = r;
    }
}

// ============ fused P|Q GEMM: [P|Q] = A @ [Wp|Wq], one A pass =============
__launch_bounds__(256, 3)
__global__ void gemm_pq_kernel(const float* __restrict__ A, int M,
                               const float* __restrict__ Wp_,  // [64][64]
                               const float* __restrict__ Wq_,  // [64][64]
                               float* __restrict__ Pout, float* __restrict__ Qout) {
    __shared__ float w_lds[64 * 128];
    __shared__ float e_lds[64 * 68];
    const int tid = threadIdx.x;
    for (int i = tid; i < 8192; i += 256) {
        const int k = i >> 7, c = i & 127;
        w_lds[i] = (c < 64) ? Wp_[k * 64 + c] : Wq_[k * 64 + (c - 64)];
    }
    const int te = tid & 15;
    const int tc = tid >> 4;
    const int srow = tid >> 2, shalf = tid & 3;
    const int ntiles = (M + 63) >> 6;

    for (int t = blockIdx.x; t < ntiles; t += gridDim.x) {
        const int base = t << 6;
        __syncthreads();
        {
            int g = base + srow;
            if (g > M - 1) g = M - 1;
            const float4* src = (const float4*)(A + (size_t)g * 64) + shalf * 4;
            float4* dst = (float4*)&e_lds[srow * 68 + shalf * 16];
            #pragma unroll
            for (int j = 0; j < 4; ++j) dst[j] = src[j];
        }
        __syncthreads();

        float4 acc0[4], acc1[4];
        #pragma unroll
        for (int i = 0; i < 4; ++i) {
            acc0[i] = make_float4(0.f, 0.f, 0.f, 0.f);
            acc1[i] = make_float4(0.f, 0.f, 0.f, 0.f);
        }

        #pragma unroll 2
        for (int kq = 0; kq < 16; ++kq) {
            float evs[4][4];
            #pragma unroll
            for (int i = 0; i < 4; ++i) {
                const float4 q = *(const float4*)&e_lds[(te + 16 * i) * 68 + kq * 4];
                evs[i][0] = q.x; evs[i][1] = q.y; evs[i][2] = q.z; evs[i][3] = q.w;
            }
            #pragma unroll
            for (int j = 0; j < 4; ++j) {
                const float4 w0 = *(const float4*)&w_lds[(kq * 4 + j) * 128 + tc * 8];
                const float4 w1 = *(const float4*)&w_lds[(kq * 4 + j) * 128 + tc * 8 + 4];
                #pragma unroll
                for (int i = 0; i < 4; ++i) {
                    const float ev = evs[i][j];
                    acc0[i].x = fmaf(ev, w0.x, acc0[i].x);
                    acc0[i].y = fmaf(ev, w0.y, acc0[i].y);
                    acc0[i].z = fmaf(ev, w0.z, acc0[i].z);
                    acc0[i].w = fmaf(ev, w0.w, acc0[i].w);
                    acc1[i].x = fmaf(ev, w1.x, acc1[i].x);
                    acc1[i].y = fmaf(ev, w1.y, acc1[i].y);
                    acc1[i].z = fmaf(ev, w1.z, acc1[i].z);
                    acc1[i].w = fmaf(ev, w1.w, acc1[i].w);
                }
            }
        }

        float* __restrict__ dstbuf = (tc < 8) ? Pout : Qout;
        const int cd = (tc < 8) ? tc * 8 : (tc - 8) * 8;
        #pragma unroll
        for (int i = 0; i < 4; ++i) {
            const int g = base + te + 16 * i;
            if (g < M) {
                *(float4*)(dstbuf + (size_t)g * 64 + cd) = acc0[i];
                *(float4*)(dstbuf + (size_t)g * 64 + cd + 4) = acc1[i];
            }
        }
    }
}

// ============ CSR-fused edge GEMM + ReLU + segment-sum (64-row tiles) =====
// Round-7 fp32 algorithm, but ONE 64-row tile per block (12500 blocks):
// LDS 33.4 KB -> 4-5 blocks/CU (vs 2-3 at 128-row), i.e. ~2x independent
// phase-chains per CU to overlap the barrier-serialized stage/GEMM/epilogue/
// segsum phases. In-place safe trivially: each block reads & writes only its
// own 64 rows; no cross-block ordering.
__launch_bounds__(256, 4)
__global__ void edge_csr_kernel(const float* A,
                                const int* __restrict__ gidx,   // eidx (l==0) or null
                                const float* __restrict__ W,    // [64][64]
                                const float* __restrict__ bias, // [64]
                                const float* __restrict__ P,
                                const float* __restrict__ Q,
                                const int* __restrict__ sid,
                                const int* __restrict__ rid,
                                const int* __restrict__ row_start,
                                float* out,
                                float* __restrict__ agg) {
    __shared__ float w_lds[64 * 64];   // 16 KB
    __shared__ float e_lds[64 * 68];   // 17.4 KB
    const int tid = threadIdx.x;
    for (int i = tid; i < 4096; i += 256) w_lds[i] = W[i];
    const int te = tid & 15;
    const int tc = tid >> 4;
    const int c0 = tc * 4;
    const float4 bv = *(const float4*)(bias + c0);
    const int srow = tid >> 2, sq = tid & 3;
    const int base = blockIdx.x << 6;

    {   // stage this block's 64 rows (gather on layer 0, contiguous after)
        const int g = base + srow;
        const int src = gidx ? gidx[g] : g;
        const float4* s4 = (const float4*)(A + (size_t)src * 64) + sq * 4;
        float4* dst = (float4*)&e_lds[srow * 68 + sq * 16];
        #pragma unroll
        for (int j = 0; j < 4; ++j) dst[j] = s4[j];
    }
    __syncthreads();   // tile staged; all A reads done -> in-place safe

    float4 acc[4];
    #pragma unroll
    for (int i = 0; i < 4; ++i) acc[i] = make_float4(0.f, 0.f, 0.f, 0.f);

    #pragma unroll 2
    for (int kq = 0; kq < 16; ++kq) {
        float evs[4][4];
        #pragma unroll
        for (int i = 0; i < 4; ++i) {
            const float4 q = *(const float4*)&e_lds[(te + 16 * i) * 68 + kq * 4];
            evs[i][0] = q.x; evs[i][1] = q.y; evs[i][2] = q.z; evs[i][3] = q.w;
        }
        #pragma unroll
        for (int j = 0; j < 4; ++j) {
            const float4 wv = *(const float4*)&w_lds[(kq * 4 + j) * 64 + c0];
            #pragma unroll
            for (int i = 0; i < 4; ++i) {
                const float ev = evs[i][j];
                acc[i].x = fmaf(ev, wv.x, acc[i].x);
                acc[i].y = fmaf(ev, wv.y, acc[i].y);
                acc[i].z = fmaf(ev, wv.z, acc[i].z);
                acc[i].w = fmaf(ev, wv.w, acc[i].w);
            }
        }
    }
    __syncthreads();   // all GEMM reads of e_lds done -> reuse for outputs

    #pragma unroll
    for (int i = 0; i < 4; ++i) {
        const int e = base + te + 16 * i;
        const int s = sid[e];
        const int r = rid[e];
        const float4 pv = *(const float4*)(P + (size_t)s * 64 + c0);
        const float4 qv = *(const float4*)(Q + (size_t)r * 64 + c0);
        float4 o;
        o.x = fmaxf(acc[i].x + bv.x + pv.x + qv.x, 0.f);
        o.y = fmaxf(acc[i].y + bv.y + pv.y + qv.y, 0.f);
        o.z = fmaxf(acc[i].z + bv.z + pv.z + qv.z, 0.f);
        o.w = fmaxf(acc[i].w + bv.w + pv.w + qv.w, 0.f);
        *(float4*)(out + (size_t)e * 64 + c0) = o;
        *(float4*)&e_lds[(te + 16 * i) * 68 + c0] = o;
    }
    __syncthreads();   // output tile fully in e_lds

    // segment-sum over this tile's receiver range (rid sorted ascending)
    const int v0 = rid[base];
    const int v1 = rid[base + 63];
    const int nv = v1 - v0 + 1;
    for (int idx = tid; idx < nv * 16; idx += 256) {
        const int v  = v0 + (idx >> 4);
        const int cg = (idx & 15) * 4;
        int lo = row_start[v], hi = row_start[v + 1];
        lo = lo > base ? lo : base;
        hi = hi < base + 64 ? hi : base + 64;
        if (lo < hi) {
            float4 sum = make_float4(0.f, 0.f, 0.f, 0.f);
            for (int j = lo - base; j < hi - base; ++j) {
                const float4 ev = *(const float4*)&e_lds[j * 68 + cg];
                sum.x += ev.x; sum.y += ev.y; sum.z += ev.z; sum.w += ev.w;
            }
            float* ap = agg + (size_t)v * 64 + cg;
            atomicAdd(ap + 0, sum.x);
            atomicAdd(ap + 1, sum.y);
            atomicAdd(ap + 2, sum.z);
            atomicAdd(ap + 3, sum.w);
        }
    }
}

// ====== node update: relu([nodes | agg*inv] @ Wn + bn), K=128 =============
__launch_bounds__(256, 3)
__global__ void node_kernel(const float* __restrict__ nodes_in,
                            const float* __restrict__ agg,   // raw sums
                            const float* __restrict__ inv,   // 1/max(count,1)
                            const float* __restrict__ W,     // [128][64]
                            const float* __restrict__ bias,  // [64]
                            float* __restrict__ out) {
    __shared__ float w_lds[128 * 64];
    __shared__ float e_lds[128 * 33];
    const int tid = threadIdx.x;
    for (int i = tid; i < 8192; i += 256) w_lds[i] = W[i];
    const int te = tid & 15, tc = tid >> 4, c0 = tc * 4;
    const float4 bv = *(const float4*)(bias + c0);
    const int srow = tid >> 1, shalf = tid & 1;
    const int ntiles = (NN + 127) >> 7;

    for (int t = blockIdx.x; t < ntiles; t += gridDim.x) {
        const int base = t << 7;
        float4 acc[8];
        #pragma unroll
        for (int i = 0; i < 8; ++i) acc[i] = make_float4(0.f, 0.f, 0.f, 0.f);

        #pragma unroll
        for (int c = 0; c < 4; ++c) {
            const float* src0 = (c < 2) ? nodes_in : agg;
            const int coff = (c & 1) * 32;
            __syncthreads();
            {
                int g = base + srow;
                if (g > NN - 1) g = NN - 1;
                const float4* src = (const float4*)(src0 + (size_t)g * 64 + coff) + shalf * 4;
                const float scale = (c >= 2) ? inv[g] : 1.0f;
                float* dst = &e_lds[srow * 33 + shalf * 16];
                #pragma unroll
                for (int j = 0; j < 4; ++j) {
                    float4 v = src[j];
                    dst[j * 4 + 0] = v.x * scale; dst[j * 4 + 1] = v.y * scale;
                    dst[j * 4 + 2] = v.z * scale; dst[j * 4 + 3] = v.w * scale;
                }
            }
            __syncthreads();
            #pragma unroll 4
            for (int k = 0; k < 32; ++k) {
                const float4 wv = *(const float4*)&w_lds[(c * 32 + k) * 64 + c0];
                #pragma unroll
                for (int i = 0; i < 8; ++i) {
                    const float ev = e_lds[(te + 16 * i) * 33 + k];
                    acc[i].x = fmaf(ev, wv.x, acc[i].x);
                    acc[i].y = fmaf(ev, wv.y, acc[i].y);
                    acc[i].z = fmaf(ev, wv.z, acc[i].z);
                    acc[i].w = fmaf(ev, wv.w, acc[i].w);
                }
            }
        }

        #pragma unroll
        for (int i = 0; i < 8; ++i) {
            const int v = base + te + 16 * i;
            if (v < NN) {
                float4 o = acc[i];
                o.x = fmaxf(o.x + bv.x, 0.f); o.y = fmaxf(o.y + bv.y, 0.f);
                o.z = fmaxf(o.z + bv.z, 0.f); o.w = fmaxf(o.w + bv.w, 0.f);
                *(float4*)(out + (size_t)v * 64 + c0) = o;
            }
        }
    }
}

// ================= final: LN + MLP + projection (LDS-broadcast GEMMs) =====
__launch_bounds__(256, 2)
__global__ void final_kernel(const float* __restrict__ nodes,
                             const float* __restrict__ gamma,
                             const float* __restrict__ beta,
                             const float* __restrict__ W1, const float* __restrict__ b1,
                             const float* __restrict__ W2, const float* __restrict__ b2,
                             const float* __restrict__ Wp, const float* __restrict__ bp,
                             float* __restrict__ out) {
    __shared__ float w1_lds[64 * 128];
    __shared__ float w2_lds[128 * 64];
    __shared__ float x_lds[16 * 66];
    __shared__ float h_lds[16 * 130];
    const int tid = threadIdx.x;
    for (int i = tid; i < 8192; i += 256) w1_lds[i] = W1[i];
    for (int i = tid; i < 8192; i += 256) w2_lds[i] = W2[i];
    const int r  = tid >> 4;
    const int li = tid & 15;
    const float4 gm4 = *(const float4*)(gamma + li * 4);
    const float4 bt4 = *(const float4*)(beta + li * 4);
    const float4 b1v0 = *(const float4*)(b1 + li * 8);
    const float4 b1v1 = *(const float4*)(b1 + li * 8 + 4);
    const float4 b2v = *(const float4*)(b2 + li * 4);
    const float4 wpv = *(const float4*)(Wp + li * 4);
    const float bp0 = bp[0];

    for (int tile = blockIdx.x; tile < NN / 16; tile += gridDim.x) {
        const int vbase = tile * 16;
        const float4 xv = *(const float4*)(nodes + (size_t)(vbase + r) * 64 + li * 4);
        float s = xv.x + xv.y + xv.z + xv.w;
        #pragma unroll
        for (int off = 1; off < 16; off <<= 1) s += __shfl_xor(s, off, 16);
        const float mu = s * (1.0f / 64.0f);
        const float dx = xv.x - mu, dy = xv.y - mu, dz = xv.z - mu, dw = xv.w - mu;
        float q = dx * dx + dy * dy + dz * dz + dw * dw;
        #pragma unroll
        for (int off = 1; off < 16; off <<= 1) q += __shfl_xor(q, off, 16);
        const float rs = rsqrtf(q * (1.0f / 64.0f) + 1e-5f);
        float* xp = &x_lds[r * 66 + li * 4];
        xp[0] = dx * rs * gm4.x + bt4.x;
        xp[1] = dy * rs * gm4.y + bt4.y;
        xp[2] = dz * rs * gm4.z + bt4.z;
        xp[3] = dw * rs * gm4.w + bt4.w;
        __syncthreads();

        float4 h0 = make_float4(0.f, 0.f, 0.f, 0.f);
        float4 h1 = make_float4(0.f, 0.f, 0.f, 0.f);
        #pragma unroll 8
        for (int k = 0; k < 64; ++k) {
            const float xk = x_lds[r * 66 + k];
            const float4 w0 = *(const float4*)&w1_lds[k * 128 + li * 8];
            const float4 w1v = *(const float4*)&w1_lds[k * 128 + li * 8 + 4];
            h0.x = fmaf(xk, w0.x, h0.x); h0.y = fmaf(xk, w0.y, h0.y);
            h0.z = fmaf(xk, w0.z, h0.z); h0.w = fmaf(xk, w0.w, h0.w);
            h1.x = fmaf(xk, w1v.x, h1.x); h1.y = fmaf(xk, w1v.y, h1.y);
            h1.z = fmaf(xk, w1v.z, h1.z); h1.w = fmaf(xk, w1v.w, h1.w);
        }
        float* hp = &h_lds[r * 130 + li * 8];
        hp[0] = fmaxf(h0.x + b1v0.x, 0.f);
        hp[1] = fmaxf(h0.y + b1v0.y, 0.f);
        hp[2] = fmaxf(h0.z + b1v0.z, 0.f);
        hp[3] = fmaxf(h0.w + b1v0.w, 0.f);
        hp[4] = fmaxf(h1.x + b1v1.x, 0.f);
        hp[5] = fmaxf(h1.y + b1v1.y, 0.f);
        hp[6] = fmaxf(h1.z + b1v1.z, 0.f);
        hp[7] = fmaxf(h1.w + b1v1.w, 0.f);
        __syncthreads();

        float4 o = make_float4(0.f, 0.f, 0.f, 0.f);
        #pragma unroll 8
        for (int k = 0; k < 128; ++k) {
            const float hk = h_lds[r * 130 + k];
            const float4 w = *(const float4*)&w2_lds[k * 64 + li * 4];
            o.x = fmaf(hk, w.x, o.x); o.y = fmaf(hk, w.y, o.y);
            o.z = fmaf(hk, w.z, o.z); o.w = fmaf(hk, w.w, o.w);
        }
        float p = (o.x + b2v.x) * wpv.x + (o.y + b2v.y) * wpv.y +
                  (o.z + b2v.z) * wpv.z + (o.w + b2v.w) * wpv.w;
        #pragma unroll
        for (int off = 1; off < 16; off <<= 1) p += __shfl_xor(p, off, 16);
        if (li == 0) out[vbase + r] = p + bp0;
    }
}

extern "C" void kernel_launch(void* const* d_in, const int* in_sizes, int n_in,
                              void* d_out, int out_size, void* d_ws, size_t ws_size,
                              hipStream_t stream) {
    const float* nodes     = (const float*)d_in[0];
    const float* edges     = (const float*)d_in[1];
    const int*   senders   = (const int*)d_in[2];
    const int*   receivers = (const int*)d_in[3];
    const float* We        = (const float*)d_in[4];
    const float* be        = (const float*)d_in[5];
    const float* Wn        = (const float*)d_in[6];
    const float* bn        = (const float*)d_in[7];
    const float* gamma     = (const float*)d_in[8];
    const float* beta      = (const float*)d_in[9];
    const float* W1        = (const float*)d_in[10];
    const float* b1        = (const float*)d_in[11];
    const float* W2        = (const float*)d_in[12];
    const float* b2        = (const float*)d_in[13];
    const float* Wp        = (const float*)d_in[14];
    const float* bp        = (const float*)d_in[15];
    float* out = (float*)d_out;

    float* ws        = (float*)d_ws;
    float* edges_buf = ws;                                   // [NE][64]  204.8 MB (CSR order)
    float* Pbuf      = edges_buf + (size_t)NE * 64;          // [NN][64]
    float* Qbuf      = Pbuf + (size_t)NN * 64;               // [NN][64]
    float* nodes_buf = Qbuf + (size_t)NN * 64;               // [NN][64]
    float* aggbuf    = nodes_buf + (size_t)NN * 64;          // [NN][64] raw sums
    int*   cnt_i     = (int*)(aggbuf + (size_t)NN * 64);     // [NN]
    int*   row_start = cnt_i + NN;                           // [NN+1]
    int*   cursor    = row_start + NN + 1;                   // [NN]
    int*   eidx      = cursor + NN;                          // [NE]
    int*   sid       = eidx + NE;                            // [NE]
    int*   rid       = sid + NE;                             // [NE]
    int*   bsum      = rid + NE;                             // [256]
    float* inv       = (float*)(bsum + 256);                 // [NN]

    hipMemsetAsync(cnt_i, 0, NN * sizeof(int), stream);
    hipMemsetAsync(cursor, 0, NN * sizeof(int), stream);
    hist_kernel<<<(NE + 255) / 256, 256, 0, stream>>>(receivers, cnt_i);
    inv_kernel<<<(NN + 255) / 256, 256, 0, stream>>>(cnt_i, inv);
    scan1_kernel<<<196, 256, 0, stream>>>(cnt_i, row_start, bsum);
    scan2_kernel<<<1, 256, 0, stream>>>(bsum, 196);
    scan3_kernel<<<196, 256, 0, stream>>>(row_start, bsum);
    scatter_kernel<<<(NE + 255) / 256, 256, 0, stream>>>(senders, receivers, row_start,
                                                         cursor, eidx, sid, rid);

    for (int l = 0; l < 3; ++l) {
        const float* ncur = (l == 0) ? nodes : nodes_buf;
        const float* We_l = We + (size_t)l * 192 * 64;
        // [P|Q] = nodes @ [We[64:128] | We[128:192]]  (one A pass)
        gemm_pq_kernel<<<782, 256, 0, stream>>>(ncur, NN, We_l + 64 * 64, We_l + 128 * 64,
                                                Pbuf, Qbuf);
        // zero agg sums, then fused edge GEMM + aggregation (64-row tiles)
        hipMemsetAsync(aggbuf, 0, (size_t)NN * 64 * sizeof(float), stream);
        edge_csr_kernel<<<NE / 64, 256, 0, stream>>>(
            (l == 0) ? edges : edges_buf,
            (l == 0) ? eidx : (const int*)nullptr,
            We_l, be + (size_t)l * 64, Pbuf, Qbuf,
            sid, rid, row_start, edges_buf, aggbuf);
        // nodes = relu([nodes | agg*inv] @ Wn + bn)
        node_kernel<<<391, 256, 0, stream>>>(ncur, aggbuf, inv,
                                             Wn + (size_t)l * 128 * 64, bn + (size_t)l * 64,
                                             nodes_buf);
    }
    final_kernel<<<625, 256, 0, stream>>>(nodes_buf, gamma, beta,
                                          W1, b1, W2, b2, Wp, bp, out);
}

// Round 12
// 729.121 us; speedup vs baseline: 1.3103x; 1.0831x over previous
//
#include <hip/hip_runtime.h>

#define NN 50000
#define NE 800000

typedef __attribute__((ext_vector_type(8))) short bf16x8;
typedef __attribute__((ext_vector_type(4))) float f32x4;

__device__ __forceinline__ ushort f2bf(float x) {
    union { float f; unsigned u; } v; v.f = x;
    return (ushort)((v.u + 0x7FFF + ((v.u >> 16) & 1)) >> 16);
}
__device__ __forceinline__ float bf2f(ushort b) {
    union { float f; unsigned u; } v; v.u = ((unsigned)b) << 16;
    return v.f;
}
// split 8 floats -> 8 bf16 hi + 8 bf16 lo (packed as uint4 each)
__device__ __forceinline__ void split8(const float* f, uint4& h, uint4& l) {
    ushort hs[8], ls[8];
    #pragma unroll
    for (int i = 0; i < 8; ++i) {
        hs[i] = f2bf(f[i]);
        ls[i] = f2bf(f[i] - bf2f(hs[i]));
    }
    h.x = (unsigned)hs[0] | ((unsigned)hs[1] << 16);
    h.y = (unsigned)hs[2] | ((unsigned)hs[3] << 16);
    h.z = (unsigned)hs[4] | ((unsigned)hs[5] << 16);
    h.w = (unsigned)hs[6] | ((unsigned)hs[7] << 16);
    l.x = (unsigned)ls[0] | ((unsigned)ls[1] << 16);
    l.y = (unsigned)ls[2] | ((unsigned)ls[3] << 16);
    l.z = (unsigned)ls[4] | ((unsigned)ls[5] << 16);
    l.w = (unsigned)ls[6] | ((unsigned)ls[7] << 16);
}

// ================= CSR build: hist / inv / scan / scatter =================
__global__ void hist_kernel(const int* __restrict__ recv, int* __restrict__ cnt) {
    int i = blockIdx.x * 256 + threadIdx.x;
    if (i < NE) atomicAdd(&cnt[recv[i]], 1);
}

__global__ void inv_kernel(const int* __restrict__ cnt, float* __restrict__ inv) {
    int i = blockIdx.x * 256 + threadIdx.x;
    if (i < NN) inv[i] = 1.0f / (float)max(cnt[i], 1);
}

__global__ void scan1_kernel(const int* __restrict__ cnt, int* __restrict__ excl,
                             int* __restrict__ bsum) {
    const int i = blockIdx.x * 256 + threadIdx.x;
    const int lane = threadIdx.x & 63, wid = threadIdx.x >> 6;
    int orig = (i < NN) ? cnt[i] : 0;
    int x = orig;
    #pragma unroll
    for (int off = 1; off < 64; off <<= 1) {
        int y = __shfl_up(x, off, 64);
        if (lane >= off) x += y;
    }
    __shared__ int ws[4];
    if (lane == 63) ws[wid] = x;
    __syncthreads();
    int add = 0;
    for (int w = 0; w < wid; ++w) add += ws[w];
    x += add;
    if (i < NN) excl[i] = x - orig;
    if (threadIdx.x == 255) bsum[blockIdx.x] = x;
}

__global__ void scan2_kernel(int* __restrict__ bsum, int nb) {
    const int t = threadIdx.x;
    const int lane = t & 63, wid = t >> 6;
    int orig = (t < nb) ? bsum[t] : 0;
    int x = orig;
    #pragma unroll
    for (int off = 1; off < 64; off <<= 1) {
        int y = __shfl_up(x, off, 64);
        if (lane >= off) x += y;
    }
    __shared__ int ws[4];
    if (lane == 63) ws[wid] = x;
    __syncthreads();
    int add = 0;
    for (int w = 0; w < wid; ++w) add += ws[w];
    x += add;
    __syncthreads();
    if (t < nb) bsum[t] = x - orig;
}

__global__ void scan3_kernel(int* __restrict__ excl, const int* __restrict__ bsum) {
    const int i = blockIdx.x * 256 + threadIdx.x;
    if (i < NN) excl[i] += bsum[blockIdx.x];
    if (i == 0) excl[NN] = NE;
}

__global__ void scatter_kernel(const int* __restrict__ senders, const int* __restrict__ recv,
                               const int* __restrict__ row_start,
                               int* __restrict__ cursor, int* __restrict__ eidx,
                               int* __restrict__ sid, int* __restrict__ rid) {
    int i = blockIdx.x * 256 + threadIdx.x;
    if (i < NE) {
        int r = recv[i];
        int p = row_start[r] + atomicAdd(&cursor[r], 1);
        eidx[p] = i;
        sid[p] = senders[i];
        rid[p] = r;
    }
}

// ========== econv: gather fp32 edges into CSR order as bf16 hi/lo =========
__global__ void econv_kernel(const float* __restrict__ edges,
                             const int* __restrict__ eidx,
                             ushort* __restrict__ ehi, ushort* __restrict__ elo) {
    const int idx = blockIdx.x * 256 + threadIdx.x;   // 16-float chunk index
    const int p = idx >> 2, q = idx & 3;
    if (p >= NE) return;
    const float4* src = (const float4*)(edges + (size_t)eidx[p] * 64 + q * 16);
    float f[16];
    #pragma unroll
    for (int c = 0; c < 4; ++c) {
        const float4 v = src[c];
        f[c * 4 + 0] = v.x; f[c * 4 + 1] = v.y; f[c * 4 + 2] = v.z; f[c * 4 + 3] = v.w;
    }
    uint4 h0, l0, h1, l1;
    split8(f, h0, l0);
    split8(f + 8, h1, l1);
    uint4* dh = (uint4*)ehi + ((size_t)p * 8 + q * 2);
    uint4* dl = (uint4*)elo + ((size_t)p * 8 + q * 2);
    dh[0] = h0; dh[1] = h1;
    dl[0] = l0; dl[1] = l1;
}

// ========== wconv: We[l][0:64] -> MFMA B-fragment order, bf16 hi/lo =======
// Wf[l][(kt*4+nt)*64 + lane][j] = W_l[(32*kt + (lane>>4)*8 + j)*64 + 16*nt + (lane&15)]
__global__ void wconv_kernel(const float* __restrict__ We,
                             ushort* __restrict__ WfH, ushort* __restrict__ WfL) {
    const int l = blockIdx.x;
    const float* W = We + (size_t)l * 192 * 64;
    ushort* oh = WfH + (size_t)l * 4096;
    ushort* ol = WfL + (size_t)l * 4096;
    for (int s = threadIdx.x; s < 512; s += 256) {
        const int ktnt = s >> 6, lane = s & 63;
        const int kt = ktnt >> 2, nt = ktnt & 3;
        const int kb = 32 * kt + (lane >> 4) * 8;
        const int c  = 16 * nt + (lane & 15);
        #pragma unroll
        for (int j = 0; j < 8; ++j) {
            const float w = W[(kb + j) * 64 + c];
            const ushort h = f2bf(w);
            oh[s * 8 + j] = h;
            ol[s * 8 + j] = f2bf(w - bf2f(h));
        }
    }
}

// ============ fused P|Q GEMM: [P|Q] = A @ [Wp|Wq], one A pass =============
__launch_bounds__(256, 3)
__global__ void gemm_pq_kernel(const float* __restrict__ A, int M,
                               const float* __restrict__ Wp_,  // [64][64]
                               const float* __restrict__ Wq_,  // [64][64]
                               float* __restrict__ Pout, float* __restrict__ Qout) {
    __shared__ float w_lds[64 * 128];
    __shared__ float e_lds[64 * 68];
    const int tid = threadIdx.x;
    for (int i = tid; i < 8192; i += 256) {
        const int k = i >> 7, c = i & 127;
        w_lds[i] = (c < 64) ? Wp_[k * 64 + c] : Wq_[k * 64 + (c - 64)];
    }
    const int te = tid & 15;
    const int tc = tid >> 4;
    const int srow = tid >> 2, shalf = tid & 3;
    const int ntiles = (M + 63) >> 6;

    for (int t = blockIdx.x; t < ntiles; t += gridDim.x) {
        const int base = t << 6;
        __syncthreads();
        {
            int g = base + srow;
            if (g > M - 1) g = M - 1;
            const float4* src = (const float4*)(A + (size_t)g * 64) + shalf * 4;
            float4* dst = (float4*)&e_lds[srow * 68 + shalf * 16];
            #pragma unroll
            for (int j = 0; j < 4; ++j) dst[j] = src[j];
        }
        __syncthreads();

        float4 acc0[4], acc1[4];
        #pragma unroll
        for (int i = 0; i < 4; ++i) {
            acc0[i] = make_float4(0.f, 0.f, 0.f, 0.f);
            acc1[i] = make_float4(0.f, 0.f, 0.f, 0.f);
        }

        #pragma unroll 2
        for (int kq = 0; kq < 16; ++kq) {
            float evs[4][4];
            #pragma unroll
            for (int i = 0; i < 4; ++i) {
                const float4 q = *(const float4*)&e_lds[(te + 16 * i) * 68 + kq * 4];
                evs[i][0] = q.x; evs[i][1] = q.y; evs[i][2] = q.z; evs[i][3] = q.w;
            }
            #pragma unroll
            for (int j = 0; j < 4; ++j) {
                const float4 w0 = *(const float4*)&w_lds[(kq * 4 + j) * 128 + tc * 8];
                const float4 w1 = *(const float4*)&w_lds[(kq * 4 + j) * 128 + tc * 8 + 4];
                #pragma unroll
                for (int i = 0; i < 4; ++i) {
                    const float ev = evs[i][j];
                    acc0[i].x = fmaf(ev, w0.x, acc0[i].x);
                    acc0[i].y = fmaf(ev, w0.y, acc0[i].y);
                    acc0[i].z = fmaf(ev, w0.z, acc0[i].z);
                    acc0[i].w = fmaf(ev, w0.w, acc0[i].w);
                    acc1[i].x = fmaf(ev, w1.x, acc1[i].x);
                    acc1[i].y = fmaf(ev, w1.y, acc1[i].y);
                    acc1[i].z = fmaf(ev, w1.z, acc1[i].z);
                    acc1[i].w = fmaf(ev, w1.w, acc1[i].w);
                }
            }
        }

        float* __restrict__ dstbuf = (tc < 8) ? Pout : Qout;
        const int cd = (tc < 8) ? tc * 8 : (tc - 8) * 8;
        #pragma unroll
        for (int i = 0; i < 4; ++i) {
            const int g = base + te + 16 * i;
            if (g < M) {
                *(float4*)(dstbuf + (size_t)g * 64 + cd) = acc0[i];
                *(float4*)(dstbuf + (size_t)g * 64 + cd + 4) = acc1[i];
            }
        }
    }
}

// ===== CSR-fused edge GEMM (split-bf16 MFMA, bf16-resident edges) =========
// One 64-row tile per block. A tiles (hi/lo bf16) staged to LDS with XOR
// swizzle byte^=((row&7)<<4) applied at BOTH ds_write and ds_read (HBM
// layout stays linear). W comes from pre-converted frag-order bf16 buffers
// (global, L1-resident) -> zero W LDS traffic, no 64-VGPR W residency.
// 3-term split product (numerics proven round 10, absmax 4.9e-4).
// Epilogue: C-frag layout col=lane&15,row=(lane>>4)*4+reg [m89]; outputs
// stash'd fp32 in LDS for segsum; packed to bf16 hi/lo for next layer
// (write_out=0 on the last layer: edges are dead after aggregation).
// In-place safe: block reads only its own 64 rows (complete at barrier 1)
// and writes only those rows (after barrier 2).
__launch_bounds__(256, 4)
__global__ void edge_mfma_kernel(const ushort* ehi, const ushort* elo,  // alias out_*
                                 const ushort* __restrict__ WfH,
                                 const ushort* __restrict__ WfL,
                                 const float* __restrict__ bias,
                                 const float* __restrict__ P,
                                 const float* __restrict__ Q,
                                 const int* __restrict__ sid,
                                 const int* __restrict__ rid,
                                 const int* __restrict__ row_start,
                                 ushort* out_hi, ushort* out_lo,
                                 float* __restrict__ agg, int write_out) {
    __shared__ ushort a_hi[64 * 64];   // 8 KB, row stride 128 B, XOR-swizzled
    __shared__ ushort a_lo[64 * 64];   // 8 KB
    __shared__ float  stash[64 * 68];  // 17.4 KB fp32 outputs
    const int tid  = threadIdx.x;
    const int lane = tid & 63;
    const int w    = tid >> 6;
    const int base = blockIdx.x << 6;

    // ---- stage: thread -> row r=tid>>2, quad q=tid&3 (32 B of hi + lo) ----
    {
        const int r = tid >> 2, q = tid & 3;
        const uint4* sh = (const uint4*)ehi + ((size_t)(base + r) * 8 + q * 2);
        const uint4* sl = (const uint4*)elo + ((size_t)(base + r) * 8 + q * 2);
        const uint4 h0 = sh[0], h1 = sh[1], l0 = sl[0], l1 = sl[1];
        const int sw = (r & 7) << 4;
        char* dh = (char*)a_hi + r * 128;
        char* dl = (char*)a_lo + r * 128;
        *(uint4*)(dh + ((q * 32) ^ sw))      = h0;
        *(uint4*)(dh + ((q * 32 + 16) ^ sw)) = h1;
        *(uint4*)(dl + ((q * 32) ^ sw))      = l0;
        *(uint4*)(dl + ((q * 32 + 16) ^ sw)) = l1;
    }
    const int colC = lane & 15;
    float bv[4];
    #pragma unroll
    for (int nt = 0; nt < 4; ++nt) bv[nt] = bias[16 * nt + colC];
    __syncthreads();   // tile staged; all A reads done -> in-place safe

    // ---- MFMA: wave w owns rows w*16 .. w*16+15 ----
    f32x4 acc[4];
    #pragma unroll
    for (int nt = 0; nt < 4; ++nt) acc[nt] = (f32x4)0.0f;
    {
        const int rowA = lane & 15, kg = lane >> 4;
        const int arow = w * 16 + rowA;
        const int sw = (rowA & 7) << 4;
        #pragma unroll
        for (int kt = 0; kt < 2; ++kt) {
            const int off = arow * 128 + (((kt * 64) + kg * 16) ^ sw);
            const bf16x8 ah = *(const bf16x8*)((const char*)a_hi + off);
            const bf16x8 al = *(const bf16x8*)((const char*)a_lo + off);
            #pragma unroll
            for (int nt = 0; nt < 4; ++nt) {
                const bf16x8 wH = *(const bf16x8*)(WfH + ((kt * 4 + nt) * 64 + lane) * 8);
                const bf16x8 wL = *(const bf16x8*)(WfL + ((kt * 4 + nt) * 64 + lane) * 8);
                acc[nt] = __builtin_amdgcn_mfma_f32_16x16x32_bf16(ah, wH, acc[nt], 0, 0, 0);
                acc[nt] = __builtin_amdgcn_mfma_f32_16x16x32_bf16(ah, wL, acc[nt], 0, 0, 0);
                acc[nt] = __builtin_amdgcn_mfma_f32_16x16x32_bf16(al, wH, acc[nt], 0, 0, 0);
            }
        }
    }

    // ---- epilogue: bias + P[s] + Q[r] + relu -> stash (fp32) ----
    {
        const int rbase = w * 16 + (lane >> 4) * 4;
        #pragma unroll
        for (int j = 0; j < 4; ++j) {
            const int row = rbase + j;
            const int e = base + row;
            const int s = sid[e];
            const int r_ = rid[e];
            #pragma unroll
            for (int nt = 0; nt < 4; ++nt) {
                const int c = 16 * nt + colC;
                float o = acc[nt][j] + bv[nt]
                        + P[(size_t)s * 64 + c] + Q[(size_t)r_ * 64 + c];
                stash[row * 68 + c] = fmaxf(o, 0.f);
            }
        }
    }
    __syncthreads();   // output tile fully in stash

    // ---- segment-sum over this tile's receiver range -> atomics ----
    {
        const int v0 = rid[base];
        const int v1 = rid[base + 63];
        const int nv = v1 - v0 + 1;
        for (int idx = tid; idx < nv * 16; idx += 256) {
            const int v  = v0 + (idx >> 4);
            const int cg = (idx & 15) * 4;
            int lo = row_start[v], hi = row_start[v + 1];
            lo = lo > base ? lo : base;
            hi = hi < base + 64 ? hi : base + 64;
            if (lo < hi) {
                float4 sum = make_float4(0.f, 0.f, 0.f, 0.f);
                for (int j = lo - base; j < hi - base; ++j) {
                    const float4 ev = *(const float4*)&stash[j * 68 + cg];
                    sum.x += ev.x; sum.y += ev.y; sum.z += ev.z; sum.w += ev.w;
                }
                float* ap = agg + (size_t)v * 64 + cg;
                atomicAdd(ap + 0, sum.x);
                atomicAdd(ap + 1, sum.y);
                atomicAdd(ap + 2, sum.z);
                atomicAdd(ap + 3, sum.w);
            }
        }
    }

    // ---- pack: stash fp32 -> bf16 hi/lo, coalesced linear stores ----
    if (write_out) {
        const int r = tid >> 2, q = tid & 3;
        const float* sp = &stash[r * 68 + q * 16];
        float f[16];
        #pragma unroll
        for (int c = 0; c < 4; ++c) {
            const float4 v = *(const float4*)(sp + c * 4);
            f[c * 4 + 0] = v.x; f[c * 4 + 1] = v.y; f[c * 4 + 2] = v.z; f[c * 4 + 3] = v.w;
        }
        uint4 h0, l0, h1, l1;
        split8(f, h0, l0);
        split8(f + 8, h1, l1);
        uint4* dh = (uint4*)out_hi + ((size_t)(base + r) * 8 + q * 2);
        uint4* dl = (uint4*)out_lo + ((size_t)(base + r) * 8 + q * 2);
        dh[0] = h0; dh[1] = h1;
        dl[0] = l0; dl[1] = l1;
    }
}

// ====== node update: relu([nodes | agg*inv] @ Wn + bn), K=128 =============
__launch_bounds__(256, 3)
__global__ void node_kernel(const float* __restrict__ nodes_in,
                            const float* __restrict__ agg,   // raw sums
                            const float* __restrict__ inv,   // 1/max(count,1)
                            const float* __restrict__ W,     // [128][64]
                            const float* __restrict__ bias,  // [64]
                            float* __restrict__ out) {
    __shared__ float w_lds[128 * 64];
    __shared__ float e_lds[128 * 33];
    const int tid = threadIdx.x;
    for (int i = tid; i < 8192; i += 256) w_lds[i] = W[i];
    const int te = tid & 15, tc = tid >> 4, c0 = tc * 4;
    const float4 bv = *(const float4*)(bias + c0);
    const int srow = tid >> 1, shalf = tid & 1;
    const int ntiles = (NN + 127) >> 7;

    for (int t = blockIdx.x; t < ntiles; t += gridDim.x) {
        const int base = t << 7;
        float4 acc[8];
        #pragma unroll
        for (int i = 0; i < 8; ++i) acc[i] = make_float4(0.f, 0.f, 0.f, 0.f);

        #pragma unroll
        for (int c = 0; c < 4; ++c) {
            const float* src0 = (c < 2) ? nodes_in : agg;
            const int coff = (c & 1) * 32;
            __syncthreads();
            {
                int g = base + srow;
                if (g > NN - 1) g = NN - 1;
                const float4* src = (const float4*)(src0 + (size_t)g * 64 + coff) + shalf * 4;
                const float scale = (c >= 2) ? inv[g] : 1.0f;
                float* dst = &e_lds[srow * 33 + shalf * 16];
                #pragma unroll
                for (int j = 0; j < 4; ++j) {
                    float4 v = src[j];
                    dst[j * 4 + 0] = v.x * scale; dst[j * 4 + 1] = v.y * scale;
                    dst[j * 4 + 2] = v.z * scale; dst[j * 4 + 3] = v.w * scale;
                }
            }
            __syncthreads();
            #pragma unroll 4
            for (int k = 0; k < 32; ++k) {
                const float4 wv = *(const float4*)&w_lds[(c * 32 + k) * 64 + c0];
                #pragma unroll
                for (int i = 0; i < 8; ++i) {
                    const float ev = e_lds[(te + 16 * i) * 33 + k];
                    acc[i].x = fmaf(ev, wv.x, acc[i].x);
                    acc[i].y = fmaf(ev, wv.y, acc[i].y);
                    acc[i].z = fmaf(ev, wv.z, acc[i].z);
                    acc[i].w = fmaf(ev, wv.w, acc[i].w);
                }
            }
        }

        #pragma unroll
        for (int i = 0; i < 8; ++i) {
            const int v = base + te + 16 * i;
            if (v < NN) {
                float4 o = acc[i];
                o.x = fmaxf(o.x + bv.x, 0.f); o.y = fmaxf(o.y + bv.y, 0.f);
                o.z = fmaxf(o.z + bv.z, 0.f); o.w = fmaxf(o.w + bv.w, 0.f);
                *(float4*)(out + (size_t)v * 64 + c0) = o;
            }
        }
    }
}

// ================= final: LN + MLP + projection (LDS-broadcast GEMMs) =====
__launch_bounds__(256, 2)
__global__ void final_kernel(const float* __restrict__ nodes,
                             const float* __restrict__ gamma,
                             const float* __restrict__ beta,
                             const float* __restrict__ W1, const float* __restrict__ b1,
                             const float* __restrict__ W2, const float* __restrict__ b2,
                             const float* __restrict__ Wp, const float* __restrict__ bp,
                             float* __restrict__ out) {
    __shared__ float w1_lds[64 * 128];
    __shared__ float w2_lds[128 * 64];
    __shared__ float x_lds[16 * 66];
    __shared__ float h_lds[16 * 130];
    const int tid = threadIdx.x;
    for (int i = tid; i < 8192; i += 256) w1_lds[i] = W1[i];
    for (int i = tid; i < 8192; i += 256) w2_lds[i] = W2[i];
    const int r  = tid >> 4;
    const int li = tid & 15;
    const float4 gm4 = *(const float4*)(gamma + li * 4);
    const float4 bt4 = *(const float4*)(beta + li * 4);
    const float4 b1v0 = *(const float4*)(b1 + li * 8);
    const float4 b1v1 = *(const float4*)(b1 + li * 8 + 4);
    const float4 b2v = *(const float4*)(b2 + li * 4);
    const float4 wpv = *(const float4*)(Wp + li * 4);
    const float bp0 = bp[0];

    for (int tile = blockIdx.x; tile < NN / 16; tile += gridDim.x) {
        const int vbase = tile * 16;
        const float4 xv = *(const float4*)(nodes + (size_t)(vbase + r) * 64 + li * 4);
        float s = xv.x + xv.y + xv.z + xv.w;
        #pragma unroll
        for (int off = 1; off < 16; off <<= 1) s += __shfl_xor(s, off, 16);
        const float mu = s * (1.0f / 64.0f);
        const float dx = xv.x - mu, dy = xv.y - mu, dz = xv.z - mu, dw = xv.w - mu;
        float q = dx * dx + dy * dy + dz * dz + dw * dw;
        #pragma unroll
        for (int off = 1; off < 16; off <<= 1) q += __shfl_xor(q, off, 16);
        const float rs = rsqrtf(q * (1.0f / 64.0f) + 1e-5f);
        float* xp = &x_lds[r * 66 + li * 4];
        xp[0] = dx * rs * gm4.x + bt4.x;
        xp[1] = dy * rs * gm4.y + bt4.y;
        xp[2] = dz * rs * gm4.z + bt4.z;
        xp[3] = dw * rs * gm4.w + bt4.w;
        __syncthreads();

        float4 h0 = make_float4(0.f, 0.f, 0.f, 0.f);
        float4 h1 = make_float4(0.f, 0.f, 0.f, 0.f);
        #pragma unroll 8
        for (int k = 0; k < 64; ++k) {
            const float xk = x_lds[r * 66 + k];
            const float4 w0 = *(const float4*)&w1_lds[k * 128 + li * 8];
            const float4 w1v = *(const float4*)&w1_lds[k * 128 + li * 8 + 4];
            h0.x = fmaf(xk, w0.x, h0.x); h0.y = fmaf(xk, w0.y, h0.y);
            h0.z = fmaf(xk, w0.z, h0.z); h0.w = fmaf(xk, w0.w, h0.w);
            h1.x = fmaf(xk, w1v.x, h1.x); h1.y = fmaf(xk, w1v.y, h1.y);
            h1.z = fmaf(xk, w1v.z, h1.z); h1.w = fmaf(xk, w1v.w, h1.w);
        }
        float* hp = &h_lds[r * 130 + li * 8];
        hp[0] = fmaxf(h0.x + b1v0.x, 0.f);
        hp[1] = fmaxf(h0.y + b1v0.y, 0.f);
        hp[2] = fmaxf(h0.z + b1v0.z, 0.f);
        hp[3] = fmaxf(h0.w + b1v0.w, 0.f);
        hp[4] = fmaxf(h1.x + b1v1.x, 0.f);
        hp[5] = fmaxf(h1.y + b1v1.y, 0.f);
        hp[6] = fmaxf(h1.z + b1v1.z, 0.f);
        hp[7] = fmaxf(h1.w + b1v1.w, 0.f);
        __syncthreads();

        float4 o = make_float4(0.f, 0.f, 0.f, 0.f);
        #pragma unroll 8
        for (int k = 0; k < 128; ++k) {
            const float hk = h_lds[r * 130 + k];
            const float4 w = *(const float4*)&w2_lds[k * 64 + li * 4];
            o.x = fmaf(hk, w.x, o.x); o.y = fmaf(hk, w.y, o.y);
            o.z = fmaf(hk, w.z, o.z); o.w = fmaf(hk, w.w, o.w);
        }
        float p = (o.x + b2v.x) * wpv.x + (o.y + b2v.y) * wpv.y +
                  (o.z + b2v.z) * wpv.z + (o.w + b2v.w) * wpv.w;
        #pragma unroll
        for (int off = 1; off < 16; off <<= 1) p += __shfl_xor(p, off, 16);
        if (li == 0) out[vbase + r] = p + bp0;
    }
}

extern "C" void kernel_launch(void* const* d_in, const int* in_sizes, int n_in,
                              void* d_out, int out_size, void* d_ws, size_t ws_size,
                              hipStream_t stream) {
    const float* nodes     = (const float*)d_in[0];
    const float* edges     = (const float*)d_in[1];
    const int*   senders   = (const int*)d_in[2];
    const int*   receivers = (const int*)d_in[3];
    const float* We        = (const float*)d_in[4];
    const float* be        = (const float*)d_in[5];
    const float* Wn        = (const float*)d_in[6];
    const float* bn        = (const float*)d_in[7];
    const float* gamma     = (const float*)d_in[8];
    const float* beta      = (const float*)d_in[9];
    const float* W1        = (const float*)d_in[10];
    const float* b1        = (const float*)d_in[11];
    const float* W2        = (const float*)d_in[12];
    const float* b2        = (const float*)d_in[13];
    const float* Wp        = (const float*)d_in[14];
    const float* bp        = (const float*)d_in[15];
    float* out = (float*)d_out;

    char* ws = (char*)d_ws;
    ushort* ehi      = (ushort*)ws;                          // [NE*64] 102.4 MB (CSR)
    ushort* elo      = ehi + (size_t)NE * 64;                // [NE*64] 102.4 MB
    float* Pbuf      = (float*)(elo + (size_t)NE * 64);      // [NN][64]
    float* Qbuf      = Pbuf + (size_t)NN * 64;               // [NN][64]
    float* nodes_buf = Qbuf + (size_t)NN * 64;               // [NN][64]
    float* aggbuf    = nodes_buf + (size_t)NN * 64;          // [NN][64] raw sums
    int*   cnt_i     = (int*)(aggbuf + (size_t)NN * 64);     // [NN]
    int*   row_start = cnt_i + NN;                           // [NN+1]
    int*   cursor    = row_start + NN + 1;                   // [NN]
    int*   eidx      = cursor + NN;                          // [NE]
    int*   sid       = eidx + NE;                            // [NE]
    int*   rid       = sid + NE;                             // [NE]
    int*   bsum      = rid + NE;                             // [256]
    float* inv       = (float*)(bsum + 256);                 // [NN]
    ushort* WfH      = (ushort*)(inv + NN);                  // [3*4096]
    ushort* WfL      = WfH + 3 * 4096;                       // [3*4096]

    hipMemsetAsync(cnt_i, 0, NN * sizeof(int), stream);
    hipMemsetAsync(cursor, 0, NN * sizeof(int), stream);
    hist_kernel<<<(NE + 255) / 256, 256, 0, stream>>>(receivers, cnt_i);
    inv_kernel<<<(NN + 255) / 256, 256, 0, stream>>>(cnt_i, inv);
    scan1_kernel<<<196, 256, 0, stream>>>(cnt_i, row_start, bsum);
    scan2_kernel<<<1, 256, 0, stream>>>(bsum, 196);
    scan3_kernel<<<196, 256, 0, stream>>>(row_start, bsum);
    scatter_kernel<<<(NE + 255) / 256, 256, 0, stream>>>(senders, receivers, row_start,
                                                         cursor, eidx, sid, rid);
    // one-time conversions: edges -> CSR bf16 hi/lo; We[0:64] -> frag order
    econv_kernel<<<NE * 4 / 256, 256, 0, stream>>>(edges, eidx, ehi, elo);
    wconv_kernel<<<3, 256, 0, stream>>>(We, WfH, WfL);

    for (int l = 0; l < 3; ++l) {
        const float* ncur = (l == 0) ? nodes : nodes_buf;
        const float* We_l = We + (size_t)l * 192 * 64;
        // [P|Q] = nodes @ [We[64:128] | We[128:192]]  (one A pass)
        gemm_pq_kernel<<<782, 256, 0, stream>>>(ncur, NN, We_l + 64 * 64, We_l + 128 * 64,
                                                Pbuf, Qbuf);
        // zero agg sums, then fused edge GEMM (MFMA) + aggregation
        hipMemsetAsync(aggbuf, 0, (size_t)NN * 64 * sizeof(float), stream);
        edge_mfma_kernel<<<NE / 64, 256, 0, stream>>>(
            ehi, elo, WfH + (size_t)l * 4096, WfL + (size_t)l * 4096,
            be + (size_t)l * 64, Pbuf, Qbuf, sid, rid, row_start,
            ehi, elo, aggbuf, (l < 2) ? 1 : 0);
        // nodes = relu([nodes | agg*inv] @ Wn + bn)
        node_kernel<<<391, 256, 0, stream>>>(ncur, aggbuf, inv,
                                             Wn + (size_t)l * 128 * 64, bn + (size_t)l * 64,
                                             nodes_buf);
    }
    final_kernel<<<625, 256, 0, stream>>>(nodes_buf, gamma, beta,
                                          W1, b1, W2, b2, Wp, bp, out);
}

// Round 13
// 651.271 us; speedup vs baseline: 1.4669x; 1.1195x over previous
//
#include <hip/hip_runtime.h>

#define NN 50000
#define NE 800000

typedef __attribute__((ext_vector_type(8))) short bf16x8;
typedef __attribute__((ext_vector_type(4))) float f32x4;

__device__ __forceinline__ ushort f2bf(float x) {
    union { float f; unsigned u; } v; v.f = x;
    return (ushort)((v.u + 0x7FFF + ((v.u >> 16) & 1)) >> 16);
}
__device__ __forceinline__ float bf2f(ushort b) {
    union { float f; unsigned u; } v; v.u = ((unsigned)b) << 16;
    return v.f;
}
// pack 8 floats -> 8 bf16 in a uint4
__device__ __forceinline__ uint4 pack8(const float* f) {
    ushort hs[8];
    #pragma unroll
    for (int i = 0; i < 8; ++i) hs[i] = f2bf(f[i]);
    uint4 h;
    h.x = (unsigned)hs[0] | ((unsigned)hs[1] << 16);
    h.y = (unsigned)hs[2] | ((unsigned)hs[3] << 16);
    h.z = (unsigned)hs[4] | ((unsigned)hs[5] << 16);
    h.w = (unsigned)hs[6] | ((unsigned)hs[7] << 16);
    return h;
}

// ================= CSR build: hist / inv / scan / scatter =================
__global__ void hist_kernel(const int* __restrict__ recv, int* __restrict__ cnt) {
    int i = blockIdx.x * 256 + threadIdx.x;
    if (i < NE) atomicAdd(&cnt[recv[i]], 1);
}

__global__ void inv_kernel(const int* __restrict__ cnt, float* __restrict__ inv) {
    int i = blockIdx.x * 256 + threadIdx.x;
    if (i < NN) inv[i] = 1.0f / (float)max(cnt[i], 1);
}

__global__ void scan1_kernel(const int* __restrict__ cnt, int* __restrict__ excl,
                             int* __restrict__ bsum) {
    const int i = blockIdx.x * 256 + threadIdx.x;
    const int lane = threadIdx.x & 63, wid = threadIdx.x >> 6;
    int orig = (i < NN) ? cnt[i] : 0;
    int x = orig;
    #pragma unroll
    for (int off = 1; off < 64; off <<= 1) {
        int y = __shfl_up(x, off, 64);
        if (lane >= off) x += y;
    }
    __shared__ int ws[4];
    if (lane == 63) ws[wid] = x;
    __syncthreads();
    int add = 0;
    for (int w = 0; w < wid; ++w) add += ws[w];
    x += add;
    if (i < NN) excl[i] = x - orig;
    if (threadIdx.x == 255) bsum[blockIdx.x] = x;
}

__global__ void scan2_kernel(int* __restrict__ bsum, int nb) {
    const int t = threadIdx.x;
    const int lane = t & 63, wid = t >> 6;
    int orig = (t < nb) ? bsum[t] : 0;
    int x = orig;
    #pragma unroll
    for (int off = 1; off < 64; off <<= 1) {
        int y = __shfl_up(x, off, 64);
        if (lane >= off) x += y;
    }
    __shared__ int ws[4];
    if (lane == 63) ws[wid] = x;
    __syncthreads();
    int add = 0;
    for (int w = 0; w < wid; ++w) add += ws[w];
    x += add;
    __syncthreads();
    if (t < nb) bsum[t] = x - orig;
}

__global__ void scan3_kernel(int* __restrict__ excl, const int* __restrict__ bsum) {
    const int i = blockIdx.x * 256 + threadIdx.x;
    if (i < NN) excl[i] += bsum[blockIdx.x];
    if (i == 0) excl[NN] = NE;
}

__global__ void scatter_kernel(const int* __restrict__ senders, const int* __restrict__ recv,
                               const int* __restrict__ row_start,
                               int* __restrict__ cursor, int* __restrict__ eidx,
                               int* __restrict__ sid, int* __restrict__ rid) {
    int i = blockIdx.x * 256 + threadIdx.x;
    if (i < NE) {
        int r = recv[i];
        int p = row_start[r] + atomicAdd(&cursor[r], 1);
        eidx[p] = i;
        sid[p] = senders[i];
        rid[p] = r;
    }
}

// ========== econv: gather fp32 edges into CSR order as bf16 ===============
__global__ void econv_kernel(const float* __restrict__ edges,
                             const int* __restrict__ eidx,
                             ushort* __restrict__ ehi) {
    const int idx = blockIdx.x * 256 + threadIdx.x;   // 16-float chunk index
    const int p = idx >> 2, q = idx & 3;
    if (p >= NE) return;
    const float4* src = (const float4*)(edges + (size_t)eidx[p] * 64 + q * 16);
    float f[16];
    #pragma unroll
    for (int c = 0; c < 4; ++c) {
        const float4 v = src[c];
        f[c * 4 + 0] = v.x; f[c * 4 + 1] = v.y; f[c * 4 + 2] = v.z; f[c * 4 + 3] = v.w;
    }
    uint4* dh = (uint4*)ehi + ((size_t)p * 8 + q * 2);
    dh[0] = pack8(f);
    dh[1] = pack8(f + 8);
}

// ========== wconv: We[l][0:64] -> MFMA B-fragment order, bf16 hi/lo =======
__global__ void wconv_kernel(const float* __restrict__ We,
                             ushort* __restrict__ WfH, ushort* __restrict__ WfL) {
    const int l = blockIdx.x;
    const float* W = We + (size_t)l * 192 * 64;
    ushort* oh = WfH + (size_t)l * 4096;
    ushort* ol = WfL + (size_t)l * 4096;
    for (int s = threadIdx.x; s < 512; s += 256) {
        const int ktnt = s >> 6, lane = s & 63;
        const int kt = ktnt >> 2, nt = ktnt & 3;
        const int kb = 32 * kt + (lane >> 4) * 8;
        const int c  = 16 * nt + (lane & 15);
        #pragma unroll
        for (int j = 0; j < 8; ++j) {
            const float w = W[(kb + j) * 64 + c];
            const ushort h = f2bf(w);
            oh[s * 8 + j] = h;
            ol[s * 8 + j] = f2bf(w - bf2f(h));
        }
    }
}

// ============ fused P|Q GEMM: [P|Q] = A @ [Wp|Wq], one A pass =============
__launch_bounds__(256, 3)
__global__ void gemm_pq_kernel(const float* __restrict__ A, int M,
                               const float* __restrict__ Wp_,  // [64][64]
                               const float* __restrict__ Wq_,  // [64][64]
                               float* __restrict__ Pout, float* __restrict__ Qout) {
    __shared__ float w_lds[64 * 128];
    __shared__ float e_lds[64 * 68];
    const int tid = threadIdx.x;
    for (int i = tid; i < 8192; i += 256) {
        const int k = i >> 7, c = i & 127;
        w_lds[i] = (c < 64) ? Wp_[k * 64 + c] : Wq_[k * 64 + (c - 64)];
    }
    const int te = tid & 15;
    const int tc = tid >> 4;
    const int srow = tid >> 2, shalf = tid & 3;
    const int ntiles = (M + 63) >> 6;

    for (int t = blockIdx.x; t < ntiles; t += gridDim.x) {
        const int base = t << 6;
        __syncthreads();
        {
            int g = base + srow;
            if (g > M - 1) g = M - 1;
            const float4* src = (const float4*)(A + (size_t)g * 64) + shalf * 4;
            float4* dst = (float4*)&e_lds[srow * 68 + shalf * 16];
            #pragma unroll
            for (int j = 0; j < 4; ++j) dst[j] = src[j];
        }
        __syncthreads();

        float4 acc0[4], acc1[4];
        #pragma unroll
        for (int i = 0; i < 4; ++i) {
            acc0[i] = make_float4(0.f, 0.f, 0.f, 0.f);
            acc1[i] = make_float4(0.f, 0.f, 0.f, 0.f);
        }

        #pragma unroll 2
        for (int kq = 0; kq < 16; ++kq) {
            float evs[4][4];
            #pragma unroll
            for (int i = 0; i < 4; ++i) {
                const float4 q = *(const float4*)&e_lds[(te + 16 * i) * 68 + kq * 4];
                evs[i][0] = q.x; evs[i][1] = q.y; evs[i][2] = q.z; evs[i][3] = q.w;
            }
            #pragma unroll
            for (int j = 0; j < 4; ++j) {
                const float4 w0 = *(const float4*)&w_lds[(kq * 4 + j) * 128 + tc * 8];
                const float4 w1 = *(const float4*)&w_lds[(kq * 4 + j) * 128 + tc * 8 + 4];
                #pragma unroll
                for (int i = 0; i < 4; ++i) {
                    const float ev = evs[i][j];
                    acc0[i].x = fmaf(ev, w0.x, acc0[i].x);
                    acc0[i].y = fmaf(ev, w0.y, acc0[i].y);
                    acc0[i].z = fmaf(ev, w0.z, acc0[i].z);
                    acc0[i].w = fmaf(ev, w0.w, acc0[i].w);
                    acc1[i].x = fmaf(ev, w1.x, acc1[i].x);
                    acc1[i].y = fmaf(ev, w1.y, acc1[i].y);
                    acc1[i].z = fmaf(ev, w1.z, acc1[i].z);
                    acc1[i].w = fmaf(ev, w1.w, acc1[i].w);
                }
            }
        }

        float* __restrict__ dstbuf = (tc < 8) ? Pout : Qout;
        const int cd = (tc < 8) ? tc * 8 : (tc - 8) * 8;
        #pragma unroll
        for (int i = 0; i < 4; ++i) {
            const int g = base + te + 16 * i;
            if (g < M) {
                *(float4*)(dstbuf + (size_t)g * 64 + cd) = acc0[i];
                *(float4*)(dstbuf + (size_t)g * 64 + cd + 4) = acc1[i];
            }
        }
    }
}

// ===== CSR-fused edge GEMM (bf16 MFMA, bf16-resident edges) ===============
// Round-12 structure with the lo plane dropped: edges stored pure bf16;
// W stays hi/lo (2-term ah*wh + ah*wl keeps W at fp32-equivalent precision;
// A carries bf16 rounding ~2^-9 rel — predicted final absmax ~1e-3 vs
// threshold 3.5e-3). Traffic per layer: 262 MB (was 466).
__launch_bounds__(256, 6)
__global__ void edge_mfma_kernel(const ushort* ehi,                    // alias out_hi
                                 const ushort* __restrict__ WfH,
                                 const ushort* __restrict__ WfL,
                                 const float* __restrict__ bias,
                                 const float* __restrict__ P,
                                 const float* __restrict__ Q,
                                 const int* __restrict__ sid,
                                 const int* __restrict__ rid,
                                 const int* __restrict__ row_start,
                                 ushort* out_hi,
                                 float* __restrict__ agg, int write_out) {
    __shared__ ushort a_hi[64 * 64];   // 8 KB, row stride 128 B, XOR-swizzled
    __shared__ float  stash[64 * 68];  // 17.4 KB fp32 outputs
    const int tid  = threadIdx.x;
    const int lane = tid & 63;
    const int w    = tid >> 6;
    const int base = blockIdx.x << 6;

    // ---- stage: thread -> row r=tid>>2, quad q=tid&3 (32 B of hi) ----
    {
        const int r = tid >> 2, q = tid & 3;
        const uint4* sh = (const uint4*)ehi + ((size_t)(base + r) * 8 + q * 2);
        const uint4 h0 = sh[0], h1 = sh[1];
        const int sw = (r & 7) << 4;
        char* dh = (char*)a_hi + r * 128;
        *(uint4*)(dh + ((q * 32) ^ sw))      = h0;
        *(uint4*)(dh + ((q * 32 + 16) ^ sw)) = h1;
    }
    const int colC = lane & 15;
    float bv[4];
    #pragma unroll
    for (int nt = 0; nt < 4; ++nt) bv[nt] = bias[16 * nt + colC];
    __syncthreads();   // tile staged; all A reads done -> in-place safe

    // ---- MFMA: wave w owns rows w*16 .. w*16+15 ----
    f32x4 acc[4];
    #pragma unroll
    for (int nt = 0; nt < 4; ++nt) acc[nt] = (f32x4)0.0f;
    {
        const int rowA = lane & 15, kg = lane >> 4;
        const int arow = w * 16 + rowA;
        const int sw = (rowA & 7) << 4;
        #pragma unroll
        for (int kt = 0; kt < 2; ++kt) {
            const int off = arow * 128 + (((kt * 64) + kg * 16) ^ sw);
            const bf16x8 ah = *(const bf16x8*)((const char*)a_hi + off);
            #pragma unroll
            for (int nt = 0; nt < 4; ++nt) {
                const bf16x8 wH = *(const bf16x8*)(WfH + ((kt * 4 + nt) * 64 + lane) * 8);
                const bf16x8 wL = *(const bf16x8*)(WfL + ((kt * 4 + nt) * 64 + lane) * 8);
                acc[nt] = __builtin_amdgcn_mfma_f32_16x16x32_bf16(ah, wH, acc[nt], 0, 0, 0);
                acc[nt] = __builtin_amdgcn_mfma_f32_16x16x32_bf16(ah, wL, acc[nt], 0, 0, 0);
            }
        }
    }

    // ---- epilogue: bias + P[s] + Q[r] + relu -> stash (fp32) ----
    {
        const int rbase = w * 16 + (lane >> 4) * 4;
        #pragma unroll
        for (int j = 0; j < 4; ++j) {
            const int row = rbase + j;
            const int e = base + row;
            const int s = sid[e];
            const int r_ = rid[e];
            #pragma unroll
            for (int nt = 0; nt < 4; ++nt) {
                const int c = 16 * nt + colC;
                float o = acc[nt][j] + bv[nt]
                        + P[(size_t)s * 64 + c] + Q[(size_t)r_ * 64 + c];
                stash[row * 68 + c] = fmaxf(o, 0.f);
            }
        }
    }
    __syncthreads();   // output tile fully in stash

    // ---- segment-sum over this tile's receiver range -> atomics ----
    {
        const int v0 = rid[base];
        const int v1 = rid[base + 63];
        const int nv = v1 - v0 + 1;
        for (int idx = tid; idx < nv * 16; idx += 256) {
            const int v  = v0 + (idx >> 4);
            const int cg = (idx & 15) * 4;
            int lo = row_start[v], hi = row_start[v + 1];
            lo = lo > base ? lo : base;
            hi = hi < base + 64 ? hi : base + 64;
            if (lo < hi) {
                float4 sum = make_float4(0.f, 0.f, 0.f, 0.f);
                for (int j = lo - base; j < hi - base; ++j) {
                    const float4 ev = *(const float4*)&stash[j * 68 + cg];
                    sum.x += ev.x; sum.y += ev.y; sum.z += ev.z; sum.w += ev.w;
                }
                float* ap = agg + (size_t)v * 64 + cg;
                atomicAdd(ap + 0, sum.x);
                atomicAdd(ap + 1, sum.y);
                atomicAdd(ap + 2, sum.z);
                atomicAdd(ap + 3, sum.w);
            }
        }
    }

    // ---- pack: stash fp32 -> bf16, coalesced linear stores ----
    if (write_out) {
        const int r = tid >> 2, q = tid & 3;
        const float* sp = &stash[r * 68 + q * 16];
        float f[16];
        #pragma unroll
        for (int c = 0; c < 4; ++c) {
            const float4 v = *(const float4*)(sp + c * 4);
            f[c * 4 + 0] = v.x; f[c * 4 + 1] = v.y; f[c * 4 + 2] = v.z; f[c * 4 + 3] = v.w;
        }
        uint4* dh = (uint4*)out_hi + ((size_t)(base + r) * 8 + q * 2);
        dh[0] = pack8(f);
        dh[1] = pack8(f + 8);
    }
}

// ====== node update: relu([nodes | agg*inv] @ Wn + bn), K=128 =============
__launch_bounds__(256, 3)
__global__ void node_kernel(const float* __restrict__ nodes_in,
                            const float* __restrict__ agg,   // raw sums
                            const float* __restrict__ inv,   // 1/max(count,1)
                            const float* __restrict__ W,     // [128][64]
                            const float* __restrict__ bias,  // [64]
                            float* __restrict__ out) {
    __shared__ float w_lds[128 * 64];
    __shared__ float e_lds[128 * 33];
    const int tid = threadIdx.x;
    for (int i = tid; i < 8192; i += 256) w_lds[i] = W[i];
    const int te = tid & 15, tc = tid >> 4, c0 = tc * 4;
    const float4 bv = *(const float4*)(bias + c0);
    const int srow = tid >> 1, shalf = tid & 1;
    const int ntiles = (NN + 127) >> 7;

    for (int t = blockIdx.x; t < ntiles; t += gridDim.x) {
        const int base = t << 7;
        float4 acc[8];
        #pragma unroll
        for (int i = 0; i < 8; ++i) acc[i] = make_float4(0.f, 0.f, 0.f, 0.f);

        #pragma unroll
        for (int c = 0; c < 4; ++c) {
            const float* src0 = (c < 2) ? nodes_in : agg;
            const int coff = (c & 1) * 32;
            __syncthreads();
            {
                int g = base + srow;
                if (g > NN - 1) g = NN - 1;
                const float4* src = (const float4*)(src0 + (size_t)g * 64 + coff) + shalf * 4;
                const float scale = (c >= 2) ? inv[g] : 1.0f;
                float* dst = &e_lds[srow * 33 + shalf * 16];
                #pragma unroll
                for (int j = 0; j < 4; ++j) {
                    float4 v = src[j];
                    dst[j * 4 + 0] = v.x * scale; dst[j * 4 + 1] = v.y * scale;
                    dst[j * 4 + 2] = v.z * scale; dst[j * 4 + 3] = v.w * scale;
                }
            }
            __syncthreads();
            #pragma unroll 4
            for (int k = 0; k < 32; ++k) {
                const float4 wv = *(const float4*)&w_lds[(c * 32 + k) * 64 + c0];
                #pragma unroll
                for (int i = 0; i < 8; ++i) {
                    const float ev = e_lds[(te + 16 * i) * 33 + k];
                    acc[i].x = fmaf(ev, wv.x, acc[i].x);
                    acc[i].y = fmaf(ev, wv.y, acc[i].y);
                    acc[i].z = fmaf(ev, wv.z, acc[i].z);
                    acc[i].w = fmaf(ev, wv.w, acc[i].w);
                }
            }
        }

        #pragma unroll
        for (int i = 0; i < 8; ++i) {
            const int v = base + te + 16 * i;
            if (v < NN) {
                float4 o = acc[i];
                o.x = fmaxf(o.x + bv.x, 0.f); o.y = fmaxf(o.y + bv.y, 0.f);
                o.z = fmaxf(o.z + bv.z, 0.f); o.w = fmaxf(o.w + bv.w, 0.f);
                *(float4*)(out + (size_t)v * 64 + c0) = o;
            }
        }
    }
}

// ================= final: LN + MLP + projection (LDS-broadcast GEMMs) =====
__launch_bounds__(256, 2)
__global__ void final_kernel(const float* __restrict__ nodes,
                             const float* __restrict__ gamma,
                             const float* __restrict__ beta,
                             const float* __restrict__ W1, const float* __restrict__ b1,
                             const float* __restrict__ W2, const float* __restrict__ b2,
                             const float* __restrict__ Wp, const float* __restrict__ bp,
                             float* __restrict__ out) {
    __shared__ float w1_lds[64 * 128];
    __shared__ float w2_lds[128 * 64];
    __shared__ float x_lds[16 * 66];
    __shared__ float h_lds[16 * 130];
    const int tid = threadIdx.x;
    for (int i = tid; i < 8192; i += 256) w1_lds[i] = W1[i];
    for (int i = tid; i < 8192; i += 256) w2_lds[i] = W2[i];
    const int r  = tid >> 4;
    const int li = tid & 15;
    const float4 gm4 = *(const float4*)(gamma + li * 4);
    const float4 bt4 = *(const float4*)(beta + li * 4);
    const float4 b1v0 = *(const float4*)(b1 + li * 8);
    const float4 b1v1 = *(const float4*)(b1 + li * 8 + 4);
    const float4 b2v = *(const float4*)(b2 + li * 4);
    const float4 wpv = *(const float4*)(Wp + li * 4);
    const float bp0 = bp[0];

    for (int tile = blockIdx.x; tile < NN / 16; tile += gridDim.x) {
        const int vbase = tile * 16;
        const float4 xv = *(const float4*)(nodes + (size_t)(vbase + r) * 64 + li * 4);
        float s = xv.x + xv.y + xv.z + xv.w;
        #pragma unroll
        for (int off = 1; off < 16; off <<= 1) s += __shfl_xor(s, off, 16);
        const float mu = s * (1.0f / 64.0f);
        const float dx = xv.x - mu, dy = xv.y - mu, dz = xv.z - mu, dw = xv.w - mu;
        float q = dx * dx + dy * dy + dz * dz + dw * dw;
        #pragma unroll
        for (int off = 1; off < 16; off <<= 1) q += __shfl_xor(q, off, 16);
        const float rs = rsqrtf(q * (1.0f / 64.0f) + 1e-5f);
        float* xp = &x_lds[r * 66 + li * 4];
        xp[0] = dx * rs * gm4.x + bt4.x;
        xp[1] = dy * rs * gm4.y + bt4.y;
        xp[2] = dz * rs * gm4.z + bt4.z;
        xp[3] = dw * rs * gm4.w + bt4.w;
        __syncthreads();

        float4 h0 = make_float4(0.f, 0.f, 0.f, 0.f);
        float4 h1 = make_float4(0.f, 0.f, 0.f, 0.f);
        #pragma unroll 8
        for (int k = 0; k < 64; ++k) {
            const float xk = x_lds[r * 66 + k];
            const float4 w0 = *(const float4*)&w1_lds[k * 128 + li * 8];
            const float4 w1v = *(const float4*)&w1_lds[k * 128 + li * 8 + 4];
            h0.x = fmaf(xk, w0.x, h0.x); h0.y = fmaf(xk, w0.y, h0.y);
            h0.z = fmaf(xk, w0.z, h0.z); h0.w = fmaf(xk, w0.w, h0.w);
            h1.x = fmaf(xk, w1v.x, h1.x); h1.y = fmaf(xk, w1v.y, h1.y);
            h1.z = fmaf(xk, w1v.z, h1.z); h1.w = fmaf(xk, w1v.w, h1.w);
        }
        float* hp = &h_lds[r * 130 + li * 8];
        hp[0] = fmaxf(h0.x + b1v0.x, 0.f);
        hp[1] = fmaxf(h0.y + b1v0.y, 0.f);
        hp[2] = fmaxf(h0.z + b1v0.z, 0.f);
        hp[3] = fmaxf(h0.w + b1v0.w, 0.f);
        hp[4] = fmaxf(h1.x + b1v1.x, 0.f);
        hp[5] = fmaxf(h1.y + b1v1.y, 0.f);
        hp[6] = fmaxf(h1.z + b1v1.z, 0.f);
        hp[7] = fmaxf(h1.w + b1v1.w, 0.f);
        __syncthreads();

        float4 o = make_float4(0.f, 0.f, 0.f, 0.f);
        #pragma unroll 8
        for (int k = 0; k < 128; ++k) {
            const float hk = h_lds[r * 130 + k];
            const float4 w = *(const float4*)&w2_lds[k * 64 + li * 4];
            o.x = fmaf(hk, w.x, o.x); o.y = fmaf(hk, w.y, o.y);
            o.z = fmaf(hk, w.z, o.z); o.w = fmaf(hk, w.w, o.w);
        }
        float p = (o.x + b2v.x) * wpv.x + (o.y + b2v.y) * wpv.y +
                  (o.z + b2v.z) * wpv.z + (o.w + b2v.w) * wpv.w;
        #pragma unroll
        for (int off = 1; off < 16; off <<= 1) p += __shfl_xor(p, off, 16);
        if (li == 0) out[vbase + r] = p + bp0;
    }
}

extern "C" void kernel_launch(void* const* d_in, const int* in_sizes, int n_in,
                              void* d_out, int out_size, void* d_ws, size_t ws_size,
                              hipStream_t stream) {
    const float* nodes     = (const float*)d_in[0];
    const float* edges     = (const float*)d_in[1];
    const int*   senders   = (const int*)d_in[2];
    const int*   receivers = (const int*)d_in[3];
    const float* We        = (const float*)d_in[4];
    const float* be        = (const float*)d_in[5];
    const float* Wn        = (const float*)d_in[6];
    const float* bn        = (const float*)d_in[7];
    const float* gamma     = (const float*)d_in[8];
    const float* beta      = (const float*)d_in[9];
    const float* W1        = (const float*)d_in[10];
    const float* b1        = (const float*)d_in[11];
    const float* W2        = (const float*)d_in[12];
    const float* b2        = (const float*)d_in[13];
    const float* Wp        = (const float*)d_in[14];
    const float* bp        = (const float*)d_in[15];
    float* out = (float*)d_out;

    char* ws = (char*)d_ws;
    ushort* ehi      = (ushort*)ws;                          // [NE*64] 102.4 MB (CSR, bf16)
    float* Pbuf      = (float*)(ehi + (size_t)NE * 64);      // [NN][64]
    float* Qbuf      = Pbuf + (size_t)NN * 64;               // [NN][64]
    float* nodes_buf = Qbuf + (size_t)NN * 64;               // [NN][64]
    float* aggbuf    = nodes_buf + (size_t)NN * 64;          // [NN][64] raw sums
    int*   cnt_i     = (int*)(aggbuf + (size_t)NN * 64);     // [NN]
    int*   row_start = cnt_i + NN;                           // [NN+1]
    int*   cursor    = row_start + NN + 1;                   // [NN]
    int*   eidx      = cursor + NN;                          // [NE]
    int*   sid       = eidx + NE;                            // [NE]
    int*   rid       = sid + NE;                             // [NE]
    int*   bsum      = rid + NE;                             // [256]
    float* inv       = (float*)(bsum + 256);                 // [NN]
    ushort* WfH      = (ushort*)(inv + NN);                  // [3*4096]
    ushort* WfL      = WfH + 3 * 4096;                       // [3*4096]

    hipMemsetAsync(cnt_i, 0, NN * sizeof(int), stream);
    hipMemsetAsync(cursor, 0, NN * sizeof(int), stream);
    hist_kernel<<<(NE + 255) / 256, 256, 0, stream>>>(receivers, cnt_i);
    inv_kernel<<<(NN + 255) / 256, 256, 0, stream>>>(cnt_i, inv);
    scan1_kernel<<<196, 256, 0, stream>>>(cnt_i, row_start, bsum);
    scan2_kernel<<<1, 256, 0, stream>>>(bsum, 196);
    scan3_kernel<<<196, 256, 0, stream>>>(row_start, bsum);
    scatter_kernel<<<(NE + 255) / 256, 256, 0, stream>>>(senders, receivers, row_start,
                                                         cursor, eidx, sid, rid);
    // one-time conversions: edges -> CSR bf16; We[0:64] -> frag order hi/lo
    econv_kernel<<<NE * 4 / 256, 256, 0, stream>>>(edges, eidx, ehi);
    wconv_kernel<<<3, 256, 0, stream>>>(We, WfH, WfL);

    for (int l = 0; l < 3; ++l) {
        const float* ncur = (l == 0) ? nodes : nodes_buf;
        const float* We_l = We + (size_t)l * 192 * 64;
        // [P|Q] = nodes @ [We[64:128] | We[128:192]]  (one A pass)
        gemm_pq_kernel<<<782, 256, 0, stream>>>(ncur, NN, We_l + 64 * 64, We_l + 128 * 64,
                                                Pbuf, Qbuf);
        // zero agg sums, then fused edge GEMM (MFMA) + aggregation
        hipMemsetAsync(aggbuf, 0, (size_t)NN * 64 * sizeof(float), stream);
        edge_mfma_kernel<<<NE / 64, 256, 0, stream>>>(
            ehi, WfH + (size_t)l * 4096, WfL + (size_t)l * 4096,
            be + (size_t)l * 64, Pbuf, Qbuf, sid, rid, row_start,
            ehi, aggbuf, (l < 2) ? 1 : 0);
        // nodes = relu([nodes | agg*inv] @ Wn + bn)
        node_kernel<<<391, 256, 0, stream>>>(ncur, aggbuf, inv,
                                             Wn + (size_t)l * 128 * 64, bn + (size_t)l * 64,
                                             nodes_buf);
    }
    final_kernel<<<625, 256, 0, stream>>>(nodes_buf, gamma, beta,
                                          W1, b1, W2, b2, Wp, bp, out);
}

// Round 14
// 616.144 us; speedup vs baseline: 1.5505x; 1.0570x over previous
//
#include <hip/hip_runtime.h>

#define NN 50000
#define NE 800000

typedef __attribute__((ext_vector_type(8))) short bf16x8;
typedef __attribute__((ext_vector_type(4))) float f32x4;

__device__ __forceinline__ ushort f2bf(float x) {
    union { float f; unsigned u; } v; v.f = x;
    return (ushort)((v.u + 0x7FFF + ((v.u >> 16) & 1)) >> 16);
}
__device__ __forceinline__ float bf2f(ushort b) {
    union { float f; unsigned u; } v; v.u = ((unsigned)b) << 16;
    return v.f;
}
// pack 8 floats -> 8 bf16 in a uint4
__device__ __forceinline__ uint4 pack8(const float* f) {
    ushort hs[8];
    #pragma unroll
    for (int i = 0; i < 8; ++i) hs[i] = f2bf(f[i]);
    uint4 h;
    h.x = (unsigned)hs[0] | ((unsigned)hs[1] << 16);
    h.y = (unsigned)hs[2] | ((unsigned)hs[3] << 16);
    h.z = (unsigned)hs[4] | ((unsigned)hs[5] << 16);
    h.w = (unsigned)hs[6] | ((unsigned)hs[7] << 16);
    return h;
}

// ================= CSR build: hist / inv / scan / scatter =================
__global__ void hist_kernel(const int* __restrict__ recv, int* __restrict__ cnt) {
    int i = blockIdx.x * 256 + threadIdx.x;
    if (i < NE) atomicAdd(&cnt[recv[i]], 1);
}

__global__ void inv_kernel(const int* __restrict__ cnt, float* __restrict__ inv) {
    int i = blockIdx.x * 256 + threadIdx.x;
    if (i < NN) inv[i] = 1.0f / (float)max(cnt[i], 1);
}

__global__ void scan1_kernel(const int* __restrict__ cnt, int* __restrict__ excl,
                             int* __restrict__ bsum) {
    const int i = blockIdx.x * 256 + threadIdx.x;
    const int lane = threadIdx.x & 63, wid = threadIdx.x >> 6;
    int orig = (i < NN) ? cnt[i] : 0;
    int x = orig;
    #pragma unroll
    for (int off = 1; off < 64; off <<= 1) {
        int y = __shfl_up(x, off, 64);
        if (lane >= off) x += y;
    }
    __shared__ int ws[4];
    if (lane == 63) ws[wid] = x;
    __syncthreads();
    int add = 0;
    for (int w = 0; w < wid; ++w) add += ws[w];
    x += add;
    if (i < NN) excl[i] = x - orig;
    if (threadIdx.x == 255) bsum[blockIdx.x] = x;
}

__global__ void scan2_kernel(int* __restrict__ bsum, int nb) {
    const int t = threadIdx.x;
    const int lane = t & 63, wid = t >> 6;
    int orig = (t < nb) ? bsum[t] : 0;
    int x = orig;
    #pragma unroll
    for (int off = 1; off < 64; off <<= 1) {
        int y = __shfl_up(x, off, 64);
        if (lane >= off) x += y;
    }
    __shared__ int ws[4];
    if (lane == 63) ws[wid] = x;
    __syncthreads();
    int add = 0;
    for (int w = 0; w < wid; ++w) add += ws[w];
    x += add;
    __syncthreads();
    if (t < nb) bsum[t] = x - orig;
}

__global__ void scan3_kernel(int* __restrict__ excl, const int* __restrict__ bsum) {
    const int i = blockIdx.x * 256 + threadIdx.x;
    if (i < NN) excl[i] += bsum[blockIdx.x];
    if (i == 0) excl[NN] = NE;
}

__global__ void scatter_kernel(const int* __restrict__ senders, const int* __restrict__ recv,
                               const int* __restrict__ row_start,
                               int* __restrict__ cursor, int* __restrict__ eidx,
                               int* __restrict__ sid, int* __restrict__ rid) {
    int i = blockIdx.x * 256 + threadIdx.x;
    if (i < NE) {
        int r = recv[i];
        int p = row_start[r] + atomicAdd(&cursor[r], 1);
        eidx[p] = i;
        sid[p] = senders[i];
        rid[p] = r;
    }
}

// ========== wconv: We[l][0:64] -> MFMA B-fragment order, bf16 hi/lo =======
__global__ void wconv_kernel(const float* __restrict__ We,
                             ushort* __restrict__ WfH, ushort* __restrict__ WfL) {
    const int l = blockIdx.x;
    const float* W = We + (size_t)l * 192 * 64;
    ushort* oh = WfH + (size_t)l * 4096;
    ushort* ol = WfL + (size_t)l * 4096;
    for (int s = threadIdx.x; s < 512; s += 256) {
        const int ktnt = s >> 6, lane = s & 63;
        const int kt = ktnt >> 2, nt = ktnt & 3;
        const int kb = 32 * kt + (lane >> 4) * 8;
        const int c  = 16 * nt + (lane & 15);
        #pragma unroll
        for (int j = 0; j < 8; ++j) {
            const float w = W[(kb + j) * 64 + c];
            const ushort h = f2bf(w);
            oh[s * 8 + j] = h;
            ol[s * 8 + j] = f2bf(w - bf2f(h));
        }
    }
}

// ============ fused P|Q GEMM: [P|Q] = A @ [Wp|Wq], one A pass =============
__launch_bounds__(256, 3)
__global__ void gemm_pq_kernel(const float* __restrict__ A, int M,
                               const float* __restrict__ Wp_,  // [64][64]
                               const float* __restrict__ Wq_,  // [64][64]
                               float* __restrict__ Pout, float* __restrict__ Qout) {
    __shared__ float w_lds[64 * 128];
    __shared__ float e_lds[64 * 68];
    const int tid = threadIdx.x;
    for (int i = tid; i < 8192; i += 256) {
        const int k = i >> 7, c = i & 127;
        w_lds[i] = (c < 64) ? Wp_[k * 64 + c] : Wq_[k * 64 + (c - 64)];
    }
    const int te = tid & 15;
    const int tc = tid >> 4;
    const int srow = tid >> 2, shalf = tid & 3;
    const int ntiles = (M + 63) >> 6;

    for (int t = blockIdx.x; t < ntiles; t += gridDim.x) {
        const int base = t << 6;
        __syncthreads();
        {
            int g = base + srow;
            if (g > M - 1) g = M - 1;
            const float4* src = (const float4*)(A + (size_t)g * 64) + shalf * 4;
            float4* dst = (float4*)&e_lds[srow * 68 + shalf * 16];
            #pragma unroll
            for (int j = 0; j < 4; ++j) dst[j] = src[j];
        }
        __syncthreads();

        float4 acc0[4], acc1[4];
        #pragma unroll
        for (int i = 0; i < 4; ++i) {
            acc0[i] = make_float4(0.f, 0.f, 0.f, 0.f);
            acc1[i] = make_float4(0.f, 0.f, 0.f, 0.f);
        }

        #pragma unroll 2
        for (int kq = 0; kq < 16; ++kq) {
            float evs[4][4];
            #pragma unroll
            for (int i = 0; i < 4; ++i) {
                const float4 q = *(const float4*)&e_lds[(te + 16 * i) * 68 + kq * 4];
                evs[i][0] = q.x; evs[i][1] = q.y; evs[i][2] = q.z; evs[i][3] = q.w;
            }
            #pragma unroll
            for (int j = 0; j < 4; ++j) {
                const float4 w0 = *(const float4*)&w_lds[(kq * 4 + j) * 128 + tc * 8];
                const float4 w1 = *(const float4*)&w_lds[(kq * 4 + j) * 128 + tc * 8 + 4];
                #pragma unroll
                for (int i = 0; i < 4; ++i) {
                    const float ev = evs[i][j];
                    acc0[i].x = fmaf(ev, w0.x, acc0[i].x);
                    acc0[i].y = fmaf(ev, w0.y, acc0[i].y);
                    acc0[i].z = fmaf(ev, w0.z, acc0[i].z);
                    acc0[i].w = fmaf(ev, w0.w, acc0[i].w);
                    acc1[i].x = fmaf(ev, w1.x, acc1[i].x);
                    acc1[i].y = fmaf(ev, w1.y, acc1[i].y);
                    acc1[i].z = fmaf(ev, w1.z, acc1[i].z);
                    acc1[i].w = fmaf(ev, w1.w, acc1[i].w);
                }
            }
        }

        float* __restrict__ dstbuf = (tc < 8) ? Pout : Qout;
        const int cd = (tc < 8) ? tc * 8 : (tc - 8) * 8;
        #pragma unroll
        for (int i = 0; i < 4; ++i) {
            const int g = base + te + 16 * i;
            if (g < M) {
                *(float4*)(dstbuf + (size_t)g * 64 + cd) = acc0[i];
                *(float4*)(dstbuf + (size_t)g * 64 + cd + 4) = acc1[i];
            }
        }
    }
}

// ===== CSR-fused edge GEMM (bf16 MFMA) + vectorized epilogue + segsum =====
// Round-13 structure, two changes:
//  (1) l0 stages DIRECTLY from gathered fp32 edges (pack8 in stage phase) —
//      econv pass eliminated.
//  (2) epilogue split: MFMA -> stash RAW (C-frag layout) -> barrier ->
//      linear-row epilogue: each thread owns 16 contiguous floats of one
//      row, adds bias+P+Q via coalesced float4 loads (4 threads cover one
//      256B P-row contiguously), relu, writes stash back + packs bf16 out.
// In-place safe: block reads only its own 64 rows (complete at barrier 1),
// writes them only after barrier 2.
__launch_bounds__(256, 6)
__global__ void edge_mfma_kernel(const float* __restrict__ efp32,  // l0 input or null
                                 const ushort* ehi,                // l>=1 input (aliases out)
                                 const int* __restrict__ gidx,     // eidx for l0, else null
                                 const ushort* __restrict__ WfH,
                                 const ushort* __restrict__ WfL,
                                 const float* __restrict__ bias,
                                 const float* __restrict__ P,
                                 const float* __restrict__ Q,
                                 const int* __restrict__ sid,
                                 const int* __restrict__ rid,
                                 const int* __restrict__ row_start,
                                 ushort* out_hi,
                                 float* __restrict__ agg, int write_out) {
    __shared__ ushort a_hi[64 * 64];   // 8 KB, row stride 128 B, XOR-swizzled
    __shared__ float  stash[64 * 68];  // 17.4 KB fp32
    const int tid  = threadIdx.x;
    const int lane = tid & 63;
    const int w    = tid >> 6;
    const int base = blockIdx.x << 6;
    const int rr = tid >> 2, qq = tid & 3;   // linear row/quarter ownership

    // ---- stage: 32 B of bf16 per thread, swizzled LDS store ----
    {
        const int sw = (rr & 7) << 4;
        char* dh = (char*)a_hi + rr * 128;
        if (efp32) {   // l0: gather fp32 row, convert in stage
            const int src = gidx[base + rr];
            const float4* s4 = (const float4*)(efp32 + (size_t)src * 64 + qq * 16);
            float f[16];
            #pragma unroll
            for (int c = 0; c < 4; ++c) {
                const float4 v = s4[c];
                f[c * 4 + 0] = v.x; f[c * 4 + 1] = v.y;
                f[c * 4 + 2] = v.z; f[c * 4 + 3] = v.w;
            }
            *(uint4*)(dh + ((qq * 32) ^ sw))      = pack8(f);
            *(uint4*)(dh + ((qq * 32 + 16) ^ sw)) = pack8(f + 8);
        } else {
            const uint4* sh = (const uint4*)ehi + ((size_t)(base + rr) * 8 + qq * 2);
            const uint4 h0 = sh[0], h1 = sh[1];
            *(uint4*)(dh + ((qq * 32) ^ sw))      = h0;
            *(uint4*)(dh + ((qq * 32 + 16) ^ sw)) = h1;
        }
    }
    __syncthreads();   // tile staged; all input reads done -> in-place safe

    // ---- MFMA: wave w owns rows w*16 .. w*16+15 ----
    f32x4 acc[4];
    #pragma unroll
    for (int nt = 0; nt < 4; ++nt) acc[nt] = (f32x4)0.0f;
    {
        const int rowA = lane & 15, kg = lane >> 4;
        const int arow = w * 16 + rowA;
        const int sw = (rowA & 7) << 4;
        #pragma unroll
        for (int kt = 0; kt < 2; ++kt) {
            const int off = arow * 128 + (((kt * 64) + kg * 16) ^ sw);
            const bf16x8 ah = *(const bf16x8*)((const char*)a_hi + off);
            #pragma unroll
            for (int nt = 0; nt < 4; ++nt) {
                const bf16x8 wH = *(const bf16x8*)(WfH + ((kt * 4 + nt) * 64 + lane) * 8);
                const bf16x8 wL = *(const bf16x8*)(WfL + ((kt * 4 + nt) * 64 + lane) * 8);
                acc[nt] = __builtin_amdgcn_mfma_f32_16x16x32_bf16(ah, wH, acc[nt], 0, 0, 0);
                acc[nt] = __builtin_amdgcn_mfma_f32_16x16x32_bf16(ah, wL, acc[nt], 0, 0, 0);
            }
        }
    }

    // ---- stash RAW gemm results (C-frag layout: col=lane&15, row frag) ----
    {
        const int colC = lane & 15;
        const int rbase = w * 16 + (lane >> 4) * 4;
        #pragma unroll
        for (int j = 0; j < 4; ++j) {
            #pragma unroll
            for (int nt = 0; nt < 4; ++nt)
                stash[(rbase + j) * 68 + 16 * nt + colC] = acc[nt][j];
        }
    }
    __syncthreads();   // raw tile fully in stash

    // ---- linear-row epilogue: bias + P[s] + Q[r] + relu, vectorized ----
    {
        const int e = base + rr;
        const int s_ = sid[e];
        const int r_ = rid[e];
        float* sp = &stash[rr * 68 + qq * 16];
        const float4* bp4 = (const float4*)(bias + qq * 16);
        const float4* pp4 = (const float4*)(P + (size_t)s_ * 64 + qq * 16);
        const float4* qp4 = (const float4*)(Q + (size_t)r_ * 64 + qq * 16);
        float f[16];
        #pragma unroll
        for (int c = 0; c < 4; ++c) {
            const float4 sv = *(const float4*)(sp + c * 4);
            const float4 bv = bp4[c];
            const float4 pv = pp4[c];
            const float4 qv = qp4[c];
            f[c * 4 + 0] = fmaxf(sv.x + bv.x + pv.x + qv.x, 0.f);
            f[c * 4 + 1] = fmaxf(sv.y + bv.y + pv.y + qv.y, 0.f);
            f[c * 4 + 2] = fmaxf(sv.z + bv.z + pv.z + qv.z, 0.f);
            f[c * 4 + 3] = fmaxf(sv.w + bv.w + pv.w + qv.w, 0.f);
            *(float4*)(sp + c * 4) = make_float4(f[c * 4 + 0], f[c * 4 + 1],
                                                 f[c * 4 + 2], f[c * 4 + 3]);
        }
        if (write_out) {   // bf16 pack, coalesced linear stores
            uint4* dh = (uint4*)out_hi + ((size_t)e * 8 + qq * 2);
            dh[0] = pack8(f);
            dh[1] = pack8(f + 8);
        }
    }
    __syncthreads();   // final tile fully in stash

    // ---- segment-sum over this tile's receiver range -> atomics ----
    {
        const int v0 = rid[base];
        const int v1 = rid[base + 63];
        const int nv = v1 - v0 + 1;
        for (int idx = tid; idx < nv * 16; idx += 256) {
            const int v  = v0 + (idx >> 4);
            const int cg = (idx & 15) * 4;
            int lo = row_start[v], hi = row_start[v + 1];
            lo = lo > base ? lo : base;
            hi = hi < base + 64 ? hi : base + 64;
            if (lo < hi) {
                float4 sum = make_float4(0.f, 0.f, 0.f, 0.f);
                for (int j = lo - base; j < hi - base; ++j) {
                    const float4 ev = *(const float4*)&stash[j * 68 + cg];
                    sum.x += ev.x; sum.y += ev.y; sum.z += ev.z; sum.w += ev.w;
                }
                float* ap = agg + (size_t)v * 64 + cg;
                atomicAdd(ap + 0, sum.x);
                atomicAdd(ap + 1, sum.y);
                atomicAdd(ap + 2, sum.z);
                atomicAdd(ap + 3, sum.w);
            }
        }
    }
}

// ====== node update: relu([nodes | agg*inv] @ Wn + bn), K=128 =============
__launch_bounds__(256, 3)
__global__ void node_kernel(const float* __restrict__ nodes_in,
                            const float* __restrict__ agg,   // raw sums
                            const float* __restrict__ inv,   // 1/max(count,1)
                            const float* __restrict__ W,     // [128][64]
                            const float* __restrict__ bias,  // [64]
                            float* __restrict__ out) {
    __shared__ float w_lds[128 * 64];
    __shared__ float e_lds[128 * 33];
    const int tid = threadIdx.x;
    for (int i = tid; i < 8192; i += 256) w_lds[i] = W[i];
    const int te = tid & 15, tc = tid >> 4, c0 = tc * 4;
    const float4 bv = *(const float4*)(bias + c0);
    const int srow = tid >> 1, shalf = tid & 1;
    const int ntiles = (NN + 127) >> 7;

    for (int t = blockIdx.x; t < ntiles; t += gridDim.x) {
        const int base = t << 7;
        float4 acc[8];
        #pragma unroll
        for (int i = 0; i < 8; ++i) acc[i] = make_float4(0.f, 0.f, 0.f, 0.f);

        #pragma unroll
        for (int c = 0; c < 4; ++c) {
            const float* src0 = (c < 2) ? nodes_in : agg;
            const int coff = (c & 1) * 32;
            __syncthreads();
            {
                int g = base + srow;
                if (g > NN - 1) g = NN - 1;
                const float4* src = (const float4*)(src0 + (size_t)g * 64 + coff) + shalf * 4;
                const float scale = (c >= 2) ? inv[g] : 1.0f;
                float* dst = &e_lds[srow * 33 + shalf * 16];
                #pragma unroll
                for (int j = 0; j < 4; ++j) {
                    float4 v = src[j];
                    dst[j * 4 + 0] = v.x * scale; dst[j * 4 + 1] = v.y * scale;
                    dst[j * 4 + 2] = v.z * scale; dst[j * 4 + 3] = v.w * scale;
                }
            }
            __syncthreads();
            #pragma unroll 4
            for (int k = 0; k < 32; ++k) {
                const float4 wv = *(const float4*)&w_lds[(c * 32 + k) * 64 + c0];
                #pragma unroll
                for (int i = 0; i < 8; ++i) {
                    const float ev = e_lds[(te + 16 * i) * 33 + k];
                    acc[i].x = fmaf(ev, wv.x, acc[i].x);
                    acc[i].y = fmaf(ev, wv.y, acc[i].y);
                    acc[i].z = fmaf(ev, wv.z, acc[i].z);
                    acc[i].w = fmaf(ev, wv.w, acc[i].w);
                }
            }
        }

        #pragma unroll
        for (int i = 0; i < 8; ++i) {
            const int v = base + te + 16 * i;
            if (v < NN) {
                float4 o = acc[i];
                o.x = fmaxf(o.x + bv.x, 0.f); o.y = fmaxf(o.y + bv.y, 0.f);
                o.z = fmaxf(o.z + bv.z, 0.f); o.w = fmaxf(o.w + bv.w, 0.f);
                *(float4*)(out + (size_t)v * 64 + c0) = o;
            }
        }
    }
}

// ================= final: LN + MLP + projection (LDS-broadcast GEMMs) =====
__launch_bounds__(256, 2)
__global__ void final_kernel(const float* __restrict__ nodes,
                             const float* __restrict__ gamma,
                             const float* __restrict__ beta,
                             const float* __restrict__ W1, const float* __restrict__ b1,
                             const float* __restrict__ W2, const float* __restrict__ b2,
                             const float* __restrict__ Wp, const float* __restrict__ bp,
                             float* __restrict__ out) {
    __shared__ float w1_lds[64 * 128];
    __shared__ float w2_lds[128 * 64];
    __shared__ float x_lds[16 * 66];
    __shared__ float h_lds[16 * 130];
    const int tid = threadIdx.x;
    for (int i = tid; i < 8192; i += 256) w1_lds[i] = W1[i];
    for (int i = tid; i < 8192; i += 256) w2_lds[i] = W2[i];
    const int r  = tid >> 4;
    const int li = tid & 15;
    const float4 gm4 = *(const float4*)(gamma + li * 4);
    const float4 bt4 = *(const float4*)(beta + li * 4);
    const float4 b1v0 = *(const float4*)(b1 + li * 8);
    const float4 b1v1 = *(const float4*)(b1 + li * 8 + 4);
    const float4 b2v = *(const float4*)(b2 + li * 4);
    const float4 wpv = *(const float4*)(Wp + li * 4);
    const float bp0 = bp[0];

    for (int tile = blockIdx.x; tile < NN / 16; tile += gridDim.x) {
        const int vbase = tile * 16;
        const float4 xv = *(const float4*)(nodes + (size_t)(vbase + r) * 64 + li * 4);
        float s = xv.x + xv.y + xv.z + xv.w;
        #pragma unroll
        for (int off = 1; off < 16; off <<= 1) s += __shfl_xor(s, off, 16);
        const float mu = s * (1.0f / 64.0f);
        const float dx = xv.x - mu, dy = xv.y - mu, dz = xv.z - mu, dw = xv.w - mu;
        float q = dx * dx + dy * dy + dz * dz + dw * dw;
        #pragma unroll
        for (int off = 1; off < 16; off <<= 1) q += __shfl_xor(q, off, 16);
        const float rs = rsqrtf(q * (1.0f / 64.0f) + 1e-5f);
        float* xp = &x_lds[r * 66 + li * 4];
        xp[0] = dx * rs * gm4.x + bt4.x;
        xp[1] = dy * rs * gm4.y + bt4.y;
        xp[2] = dz * rs * gm4.z + bt4.z;
        xp[3] = dw * rs * gm4.w + bt4.w;
        __syncthreads();

        float4 h0 = make_float4(0.f, 0.f, 0.f, 0.f);
        float4 h1 = make_float4(0.f, 0.f, 0.f, 0.f);
        #pragma unroll 8
        for (int k = 0; k < 64; ++k) {
            const float xk = x_lds[r * 66 + k];
            const float4 w0 = *(const float4*)&w1_lds[k * 128 + li * 8];
            const float4 w1v = *(const float4*)&w1_lds[k * 128 + li * 8 + 4];
            h0.x = fmaf(xk, w0.x, h0.x); h0.y = fmaf(xk, w0.y, h0.y);
            h0.z = fmaf(xk, w0.z, h0.z); h0.w = fmaf(xk, w0.w, h0.w);
            h1.x = fmaf(xk, w1v.x, h1.x); h1.y = fmaf(xk, w1v.y, h1.y);
            h1.z = fmaf(xk, w1v.z, h1.z); h1.w = fmaf(xk, w1v.w, h1.w);
        }
        float* hp = &h_lds[r * 130 + li * 8];
        hp[0] = fmaxf(h0.x + b1v0.x, 0.f);
        hp[1] = fmaxf(h0.y + b1v0.y, 0.f);
        hp[2] = fmaxf(h0.z + b1v0.z, 0.f);
        hp[3] = fmaxf(h0.w + b1v0.w, 0.f);
        hp[4] = fmaxf(h1.x + b1v1.x, 0.f);
        hp[5] = fmaxf(h1.y + b1v1.y, 0.f);
        hp[6] = fmaxf(h1.z + b1v1.z, 0.f);
        hp[7] = fmaxf(h1.w + b1v1.w, 0.f);
        __syncthreads();

        float4 o = make_float4(0.f, 0.f, 0.f, 0.f);
        #pragma unroll 8
        for (int k = 0; k < 128; ++k) {
            const float hk = h_lds[r * 130 + k];
            const float4 w = *(const float4*)&w2_lds[k * 64 + li * 4];
            o.x = fmaf(hk, w.x, o.x); o.y = fmaf(hk, w.y, o.y);
            o.z = fmaf(hk, w.z, o.z); o.w = fmaf(hk, w.w, o.w);
        }
        float p = (o.x + b2v.x) * wpv.x + (o.y + b2v.y) * wpv.y +
                  (o.z + b2v.z) * wpv.z + (o.w + b2v.w) * wpv.w;
        #pragma unroll
        for (int off = 1; off < 16; off <<= 1) p += __shfl_xor(p, off, 16);
        if (li == 0) out[vbase + r] = p + bp0;
    }
}

extern "C" void kernel_launch(void* const* d_in, const int* in_sizes, int n_in,
                              void* d_out, int out_size, void* d_ws, size_t ws_size,
                              hipStream_t stream) {
    const float* nodes     = (const float*)d_in[0];
    const float* edges     = (const float*)d_in[1];
    const int*   senders   = (const int*)d_in[2];
    const int*   receivers = (const int*)d_in[3];
    const float* We        = (const float*)d_in[4];
    const float* be        = (const float*)d_in[5];
    const float* Wn        = (const float*)d_in[6];
    const float* bn        = (const float*)d_in[7];
    const float* gamma     = (const float*)d_in[8];
    const float* beta      = (const float*)d_in[9];
    const float* W1        = (const float*)d_in[10];
    const float* b1        = (const float*)d_in[11];
    const float* W2        = (const float*)d_in[12];
    const float* b2        = (const float*)d_in[13];
    const float* Wp        = (const float*)d_in[14];
    const float* bp        = (const float*)d_in[15];
    float* out = (float*)d_out;

    char* ws = (char*)d_ws;
    ushort* ehi      = (ushort*)ws;                          // [NE*64] 102.4 MB (CSR, bf16)
    float* Pbuf      = (float*)(ehi + (size_t)NE * 64);      // [NN][64]
    float* Qbuf      = Pbuf + (size_t)NN * 64;               // [NN][64]
    float* nodes_buf = Qbuf + (size_t)NN * 64;               // [NN][64]
    float* aggbuf    = nodes_buf + (size_t)NN * 64;          // [NN][64] raw sums
    int*   cnt_i     = (int*)(aggbuf + (size_t)NN * 64);     // [NN]
    int*   row_start = cnt_i + NN;                           // [NN+1]
    int*   cursor    = row_start + NN + 1;                   // [NN]
    int*   eidx      = cursor + NN;                          // [NE]
    int*   sid       = eidx + NE;                            // [NE]
    int*   rid       = sid + NE;                             // [NE]
    int*   bsum      = rid + NE;                             // [256]
    float* inv       = (float*)(bsum + 256);                 // [NN]
    ushort* WfH      = (ushort*)(inv + NN);                  // [3*4096]
    ushort* WfL      = WfH + 3 * 4096;                       // [3*4096]

    hipMemsetAsync(cnt_i, 0, NN * sizeof(int), stream);
    hipMemsetAsync(cursor, 0, NN * sizeof(int), stream);
    hist_kernel<<<(NE + 255) / 256, 256, 0, stream>>>(receivers, cnt_i);
    inv_kernel<<<(NN + 255) / 256, 256, 0, stream>>>(cnt_i, inv);
    scan1_kernel<<<196, 256, 0, stream>>>(cnt_i, row_start, bsum);
    scan2_kernel<<<1, 256, 0, stream>>>(bsum, 196);
    scan3_kernel<<<196, 256, 0, stream>>>(row_start, bsum);
    scatter_kernel<<<(NE + 255) / 256, 256, 0, stream>>>(senders, receivers, row_start,
                                                         cursor, eidx, sid, rid);
    // one-time: We[0:64] -> frag order hi/lo (edge l0 converts edges itself)
    wconv_kernel<<<3, 256, 0, stream>>>(We, WfH, WfL);

    for (int l = 0; l < 3; ++l) {
        const float* ncur = (l == 0) ? nodes : nodes_buf;
        const float* We_l = We + (size_t)l * 192 * 64;
        // [P|Q] = nodes @ [We[64:128] | We[128:192]]  (one A pass)
        gemm_pq_kernel<<<782, 256, 0, stream>>>(ncur, NN, We_l + 64 * 64, We_l + 128 * 64,
                                                Pbuf, Qbuf);
        // zero agg sums, then fused edge GEMM (MFMA) + aggregation
        hipMemsetAsync(aggbuf, 0, (size_t)NN * 64 * sizeof(float), stream);
        edge_mfma_kernel<<<NE / 64, 256, 0, stream>>>(
            (l == 0) ? edges : (const float*)nullptr, ehi,
            (l == 0) ? eidx : (const int*)nullptr,
            WfH + (size_t)l * 4096, WfL + (size_t)l * 4096,
            be + (size_t)l * 64, Pbuf, Qbuf, sid, rid, row_start,
            ehi, aggbuf, (l < 2) ? 1 : 0);
        // nodes = relu([nodes | agg*inv] @ Wn + bn)
        node_kernel<<<391, 256, 0, stream>>>(ncur, aggbuf, inv,
                                             Wn + (size_t)l * 128 * 64, bn + (size_t)l * 64,
                                             nodes_buf);
    }
    final_kernel<<<625, 256, 0, stream>>>(nodes_buf, gamma, beta,
                                          W1, b1, W2, b2, Wp, bp, out);
}

// Round 15
// 573.582 us; speedup vs baseline: 1.6656x; 1.0742x over previous
//
#include <hip/hip_runtime.h>

#define NN 50000
#define NE 800000

typedef __attribute__((ext_vector_type(8))) short bf16x8;
typedef __attribute__((ext_vector_type(4))) float f32x4;

__device__ __forceinline__ ushort f2bf(float x) {
    union { float f; unsigned u; } v; v.f = x;
    return (ushort)((v.u + 0x7FFF + ((v.u >> 16) & 1)) >> 16);
}
__device__ __forceinline__ float bf2f(ushort b) {
    union { float f; unsigned u; } v; v.u = ((unsigned)b) << 16;
    return v.f;
}
// pack 8 floats -> 8 bf16 in a uint4
__device__ __forceinline__ uint4 pack8(const float* f) {
    ushort hs[8];
    #pragma unroll
    for (int i = 0; i < 8; ++i) hs[i] = f2bf(f[i]);
    uint4 h;
    h.x = (unsigned)hs[0] | ((unsigned)hs[1] << 16);
    h.y = (unsigned)hs[2] | ((unsigned)hs[3] << 16);
    h.z = (unsigned)hs[4] | ((unsigned)hs[5] << 16);
    h.w = (unsigned)hs[6] | ((unsigned)hs[7] << 16);
    return h;
}
// unpack 16 bf16 (2 uint4) -> 16 floats
__device__ __forceinline__ void unpack16(const uint4* p, float* f) {
    const uint4 a = p[0], b = p[1];
    const unsigned u[8] = {a.x, a.y, a.z, a.w, b.x, b.y, b.z, b.w};
    #pragma unroll
    for (int i = 0; i < 8; ++i) {
        f[2 * i]     = bf2f((ushort)(u[i] & 0xffff));
        f[2 * i + 1] = bf2f((ushort)(u[i] >> 16));
    }
}

// ================= CSR build: hist / inv / scan / scatter =================
__global__ void hist_kernel(const int* __restrict__ recv, int* __restrict__ cnt) {
    int i = blockIdx.x * 256 + threadIdx.x;
    if (i < NE) atomicAdd(&cnt[recv[i]], 1);
}

__global__ void inv_kernel(const int* __restrict__ cnt, float* __restrict__ inv) {
    int i = blockIdx.x * 256 + threadIdx.x;
    if (i < NN) inv[i] = 1.0f / (float)max(cnt[i], 1);
}

__global__ void scan1_kernel(const int* __restrict__ cnt, int* __restrict__ excl,
                             int* __restrict__ bsum) {
    const int i = blockIdx.x * 256 + threadIdx.x;
    const int lane = threadIdx.x & 63, wid = threadIdx.x >> 6;
    int orig = (i < NN) ? cnt[i] : 0;
    int x = orig;
    #pragma unroll
    for (int off = 1; off < 64; off <<= 1) {
        int y = __shfl_up(x, off, 64);
        if (lane >= off) x += y;
    }
    __shared__ int ws[4];
    if (lane == 63) ws[wid] = x;
    __syncthreads();
    int add = 0;
    for (int w = 0; w < wid; ++w) add += ws[w];
    x += add;
    if (i < NN) excl[i] = x - orig;
    if (threadIdx.x == 255) bsum[blockIdx.x] = x;
}

__global__ void scan2_kernel(int* __restrict__ bsum, int nb) {
    const int t = threadIdx.x;
    const int lane = t & 63, wid = t >> 6;
    int orig = (t < nb) ? bsum[t] : 0;
    int x = orig;
    #pragma unroll
    for (int off = 1; off < 64; off <<= 1) {
        int y = __shfl_up(x, off, 64);
        if (lane >= off) x += y;
    }
    __shared__ int ws[4];
    if (lane == 63) ws[wid] = x;
    __syncthreads();
    int add = 0;
    for (int w = 0; w < wid; ++w) add += ws[w];
    x += add;
    __syncthreads();
    if (t < nb) bsum[t] = x - orig;
}

__global__ void scan3_kernel(int* __restrict__ excl, const int* __restrict__ bsum) {
    const int i = blockIdx.x * 256 + threadIdx.x;
    if (i < NN) excl[i] += bsum[blockIdx.x];
    if (i == 0) excl[NN] = NE;
}

__global__ void scatter_kernel(const int* __restrict__ senders, const int* __restrict__ recv,
                               const int* __restrict__ row_start,
                               int* __restrict__ cursor, int* __restrict__ eidx,
                               int* __restrict__ sid, int* __restrict__ rid) {
    int i = blockIdx.x * 256 + threadIdx.x;
    if (i < NE) {
        int r = recv[i];
        int p = row_start[r] + atomicAdd(&cursor[r], 1);
        eidx[p] = i;
        sid[p] = senders[i];
        rid[p] = r;
    }
}

// ========== wconv: We[l][0:64] -> MFMA B-fragment order, bf16 hi/lo =======
__global__ void wconv_kernel(const float* __restrict__ We,
                             ushort* __restrict__ WfH, ushort* __restrict__ WfL) {
    const int l = blockIdx.x;
    const float* W = We + (size_t)l * 192 * 64;
    ushort* oh = WfH + (size_t)l * 4096;
    ushort* ol = WfL + (size_t)l * 4096;
    for (int s = threadIdx.x; s < 512; s += 256) {
        const int ktnt = s >> 6, lane = s & 63;
        const int kt = ktnt >> 2, nt = ktnt & 3;
        const int kb = 32 * kt + (lane >> 4) * 8;
        const int c  = 16 * nt + (lane & 15);
        #pragma unroll
        for (int j = 0; j < 8; ++j) {
            const float w = W[(kb + j) * 64 + c];
            const ushort h = f2bf(w);
            oh[s * 8 + j] = h;
            ol[s * 8 + j] = f2bf(w - bf2f(h));
        }
    }
}

// ==== fused P|Q GEMM: [P|Q] = A @ [Wp|Wq], one A pass, bf16 outputs =======
__launch_bounds__(256, 3)
__global__ void gemm_pq_kernel(const float* __restrict__ A, int M,
                               const float* __restrict__ Wp_,  // [64][64]
                               const float* __restrict__ Wq_,  // [64][64]
                               ushort* __restrict__ Pout, ushort* __restrict__ Qout) {
    __shared__ float w_lds[64 * 128];
    __shared__ float e_lds[64 * 68];
    const int tid = threadIdx.x;
    for (int i = tid; i < 8192; i += 256) {
        const int k = i >> 7, c = i & 127;
        w_lds[i] = (c < 64) ? Wp_[k * 64 + c] : Wq_[k * 64 + (c - 64)];
    }
    const int te = tid & 15;
    const int tc = tid >> 4;
    const int srow = tid >> 2, shalf = tid & 3;
    const int ntiles = (M + 63) >> 6;

    for (int t = blockIdx.x; t < ntiles; t += gridDim.x) {
        const int base = t << 6;
        __syncthreads();
        {
            int g = base + srow;
            if (g > M - 1) g = M - 1;
            const float4* src = (const float4*)(A + (size_t)g * 64) + shalf * 4;
            float4* dst = (float4*)&e_lds[srow * 68 + shalf * 16];
            #pragma unroll
            for (int j = 0; j < 4; ++j) dst[j] = src[j];
        }
        __syncthreads();

        float4 acc0[4], acc1[4];
        #pragma unroll
        for (int i = 0; i < 4; ++i) {
            acc0[i] = make_float4(0.f, 0.f, 0.f, 0.f);
            acc1[i] = make_float4(0.f, 0.f, 0.f, 0.f);
        }

        #pragma unroll 2
        for (int kq = 0; kq < 16; ++kq) {
            float evs[4][4];
            #pragma unroll
            for (int i = 0; i < 4; ++i) {
                const float4 q = *(const float4*)&e_lds[(te + 16 * i) * 68 + kq * 4];
                evs[i][0] = q.x; evs[i][1] = q.y; evs[i][2] = q.z; evs[i][3] = q.w;
            }
            #pragma unroll
            for (int j = 0; j < 4; ++j) {
                const float4 w0 = *(const float4*)&w_lds[(kq * 4 + j) * 128 + tc * 8];
                const float4 w1 = *(const float4*)&w_lds[(kq * 4 + j) * 128 + tc * 8 + 4];
                #pragma unroll
                for (int i = 0; i < 4; ++i) {
                    const float ev = evs[i][j];
                    acc0[i].x = fmaf(ev, w0.x, acc0[i].x);
                    acc0[i].y = fmaf(ev, w0.y, acc0[i].y);
                    acc0[i].z = fmaf(ev, w0.z, acc0[i].z);
                    acc0[i].w = fmaf(ev, w0.w, acc0[i].w);
                    acc1[i].x = fmaf(ev, w1.x, acc1[i].x);
                    acc1[i].y = fmaf(ev, w1.y, acc1[i].y);
                    acc1[i].z = fmaf(ev, w1.z, acc1[i].z);
                    acc1[i].w = fmaf(ev, w1.w, acc1[i].w);
                }
            }
        }

        ushort* __restrict__ dstbuf = (tc < 8) ? Pout : Qout;
        const int cd = (tc < 8) ? tc * 8 : (tc - 8) * 8;
        #pragma unroll
        for (int i = 0; i < 4; ++i) {
            const int g = base + te + 16 * i;
            if (g < M) {
                float f[8] = {acc0[i].x, acc0[i].y, acc0[i].z, acc0[i].w,
                              acc1[i].x, acc1[i].y, acc1[i].z, acc1[i].w};
                *((uint4*)dstbuf + ((size_t)g * 8 + cd / 8)) = pack8(f);
            }
        }
    }
}

// ===== CSR-fused edge GEMM (bf16 MFMA) + vectorized epilogue + segsum =====
// Round-14 structure; P/Q now bf16 (half the gather bytes). Epilogue unpacks
// 2x uint4 per row-quarter. Everything else identical.
__launch_bounds__(256, 6)
__global__ void edge_mfma_kernel(const float* __restrict__ efp32,  // l0 input or null
                                 const ushort* ehi,                // l>=1 input (aliases out)
                                 const int* __restrict__ gidx,     // eidx for l0, else null
                                 const ushort* __restrict__ WfH,
                                 const ushort* __restrict__ WfL,
                                 const float* __restrict__ bias,
                                 const ushort* __restrict__ Pb,    // bf16 [NN][64]
                                 const ushort* __restrict__ Qb,    // bf16 [NN][64]
                                 const int* __restrict__ sid,
                                 const int* __restrict__ rid,
                                 const int* __restrict__ row_start,
                                 ushort* out_hi,
                                 float* __restrict__ agg, int write_out) {
    __shared__ ushort a_hi[64 * 64];   // 8 KB, row stride 128 B, XOR-swizzled
    __shared__ float  stash[64 * 68];  // 17.4 KB fp32
    const int tid  = threadIdx.x;
    const int lane = tid & 63;
    const int w    = tid >> 6;
    const int base = blockIdx.x << 6;
    const int rr = tid >> 2, qq = tid & 3;   // linear row/quarter ownership

    // ---- stage: 32 B of bf16 per thread, swizzled LDS store ----
    {
        const int sw = (rr & 7) << 4;
        char* dh = (char*)a_hi + rr * 128;
        if (efp32) {   // l0: gather fp32 row, convert in stage
            const int src = gidx[base + rr];
            const float4* s4 = (const float4*)(efp32 + (size_t)src * 64 + qq * 16);
            float f[16];
            #pragma unroll
            for (int c = 0; c < 4; ++c) {
                const float4 v = s4[c];
                f[c * 4 + 0] = v.x; f[c * 4 + 1] = v.y;
                f[c * 4 + 2] = v.z; f[c * 4 + 3] = v.w;
            }
            *(uint4*)(dh + ((qq * 32) ^ sw))      = pack8(f);
            *(uint4*)(dh + ((qq * 32 + 16) ^ sw)) = pack8(f + 8);
        } else {
            const uint4* sh = (const uint4*)ehi + ((size_t)(base + rr) * 8 + qq * 2);
            const uint4 h0 = sh[0], h1 = sh[1];
            *(uint4*)(dh + ((qq * 32) ^ sw))      = h0;
            *(uint4*)(dh + ((qq * 32 + 16) ^ sw)) = h1;
        }
    }
    __syncthreads();   // tile staged; all input reads done -> in-place safe

    // ---- MFMA: wave w owns rows w*16 .. w*16+15 ----
    f32x4 acc[4];
    #pragma unroll
    for (int nt = 0; nt < 4; ++nt) acc[nt] = (f32x4)0.0f;
    {
        const int rowA = lane & 15, kg = lane >> 4;
        const int arow = w * 16 + rowA;
        const int sw = (rowA & 7) << 4;
        #pragma unroll
        for (int kt = 0; kt < 2; ++kt) {
            const int off = arow * 128 + (((kt * 64) + kg * 16) ^ sw);
            const bf16x8 ah = *(const bf16x8*)((const char*)a_hi + off);
            #pragma unroll
            for (int nt = 0; nt < 4; ++nt) {
                const bf16x8 wH = *(const bf16x8*)(WfH + ((kt * 4 + nt) * 64 + lane) * 8);
                const bf16x8 wL = *(const bf16x8*)(WfL + ((kt * 4 + nt) * 64 + lane) * 8);
                acc[nt] = __builtin_amdgcn_mfma_f32_16x16x32_bf16(ah, wH, acc[nt], 0, 0, 0);
                acc[nt] = __builtin_amdgcn_mfma_f32_16x16x32_bf16(ah, wL, acc[nt], 0, 0, 0);
            }
        }
    }

    // ---- stash RAW gemm results (C-frag layout: col=lane&15, row frag) ----
    {
        const int colC = lane & 15;
        const int rbase = w * 16 + (lane >> 4) * 4;
        #pragma unroll
        for (int j = 0; j < 4; ++j) {
            #pragma unroll
            for (int nt = 0; nt < 4; ++nt)
                stash[(rbase + j) * 68 + 16 * nt + colC] = acc[nt][j];
        }
    }
    __syncthreads();   // raw tile fully in stash

    // ---- linear-row epilogue: bias + P[s] + Q[r] + relu, vectorized ----
    {
        const int e = base + rr;
        const int s_ = sid[e];
        const int r_ = rid[e];
        float* sp = &stash[rr * 68 + qq * 16];
        const float4* bp4 = (const float4*)(bias + qq * 16);
        float pf[16], qf[16];
        unpack16((const uint4*)(Pb + (size_t)s_ * 64 + qq * 16), pf);
        unpack16((const uint4*)(Qb + (size_t)r_ * 64 + qq * 16), qf);
        float f[16];
        #pragma unroll
        for (int c = 0; c < 4; ++c) {
            const float4 sv = *(const float4*)(sp + c * 4);
            const float4 bv = bp4[c];
            f[c * 4 + 0] = fmaxf(sv.x + bv.x + pf[c * 4 + 0] + qf[c * 4 + 0], 0.f);
            f[c * 4 + 1] = fmaxf(sv.y + bv.y + pf[c * 4 + 1] + qf[c * 4 + 1], 0.f);
            f[c * 4 + 2] = fmaxf(sv.z + bv.z + pf[c * 4 + 2] + qf[c * 4 + 2], 0.f);
            f[c * 4 + 3] = fmaxf(sv.w + bv.w + pf[c * 4 + 3] + qf[c * 4 + 3], 0.f);
            *(float4*)(sp + c * 4) = make_float4(f[c * 4 + 0], f[c * 4 + 1],
                                                 f[c * 4 + 2], f[c * 4 + 3]);
        }
        if (write_out) {   // bf16 pack, coalesced linear stores
            uint4* dh = (uint4*)out_hi + ((size_t)e * 8 + qq * 2);
            dh[0] = pack8(f);
            dh[1] = pack8(f + 8);
        }
    }
    __syncthreads();   // final tile fully in stash

    // ---- segment-sum over this tile's receiver range -> atomics ----
    {
        const int v0 = rid[base];
        const int v1 = rid[base + 63];
        const int nv = v1 - v0 + 1;
        for (int idx = tid; idx < nv * 16; idx += 256) {
            const int v  = v0 + (idx >> 4);
            const int cg = (idx & 15) * 4;
            int lo = row_start[v], hi = row_start[v + 1];
            lo = lo > base ? lo : base;
            hi = hi < base + 64 ? hi : base + 64;
            if (lo < hi) {
                float4 sum = make_float4(0.f, 0.f, 0.f, 0.f);
                for (int j = lo - base; j < hi - base; ++j) {
                    const float4 ev = *(const float4*)&stash[j * 68 + cg];
                    sum.x += ev.x; sum.y += ev.y; sum.z += ev.z; sum.w += ev.w;
                }
                float* ap = agg + (size_t)v * 64 + cg;
                atomicAdd(ap + 0, sum.x);
                atomicAdd(ap + 1, sum.y);
                atomicAdd(ap + 2, sum.z);
                atomicAdd(ap + 3, sum.w);
            }
        }
    }
}

// ====== node update: relu([nodes | agg*inv] @ Wn + bn), K=128 =============
// Zeroes agg rows in-place after reading (each row read by exactly one
// block; padding clamp rows skip the zero-write) — removes per-layer memset.
__launch_bounds__(256, 3)
__global__ void node_kernel(const float* __restrict__ nodes_in,
                            float* __restrict__ agg,         // raw sums; zeroed after read
                            const float* __restrict__ inv,   // 1/max(count,1)
                            const float* __restrict__ W,     // [128][64]
                            const float* __restrict__ bias,  // [64]
                            float* __restrict__ out) {
    __shared__ float w_lds[128 * 64];
    __shared__ float e_lds[128 * 33];
    const int tid = threadIdx.x;
    for (int i = tid; i < 8192; i += 256) w_lds[i] = W[i];
    const int te = tid & 15, tc = tid >> 4, c0 = tc * 4;
    const float4 bv = *(const float4*)(bias + c0);
    const int srow = tid >> 1, shalf = tid & 1;
    const int ntiles = (NN + 127) >> 7;

    for (int t = blockIdx.x; t < ntiles; t += gridDim.x) {
        const int base = t << 7;
        float4 acc[8];
        #pragma unroll
        for (int i = 0; i < 8; ++i) acc[i] = make_float4(0.f, 0.f, 0.f, 0.f);

        #pragma unroll
        for (int c = 0; c < 4; ++c) {
            const float* src0 = (c < 2) ? nodes_in : agg;
            const int coff = (c & 1) * 32;
            __syncthreads();
            {
                int g = base + srow;
                if (g > NN - 1) g = NN - 1;
                const float4* src = (const float4*)(src0 + (size_t)g * 64 + coff) + shalf * 4;
                const float scale = (c >= 2) ? inv[g] : 1.0f;
                float* dst = &e_lds[srow * 33 + shalf * 16];
                #pragma unroll
                for (int j = 0; j < 4; ++j) {
                    float4 v = src[j];
                    dst[j * 4 + 0] = v.x * scale; dst[j * 4 + 1] = v.y * scale;
                    dst[j * 4 + 2] = v.z * scale; dst[j * 4 + 3] = v.w * scale;
                }
                if (c >= 2 && base + srow < NN) {   // zero after read (own row only)
                    float4* wz = (float4*)(agg + (size_t)g * 64 + coff) + shalf * 4;
                    const float4 z = make_float4(0.f, 0.f, 0.f, 0.f);
                    #pragma unroll
                    for (int j = 0; j < 4; ++j) wz[j] = z;
                }
            }
            __syncthreads();
            #pragma unroll 4
            for (int k = 0; k < 32; ++k) {
                const float4 wv = *(const float4*)&w_lds[(c * 32 + k) * 64 + c0];
                #pragma unroll
                for (int i = 0; i < 8; ++i) {
                    const float ev = e_lds[(te + 16 * i) * 33 + k];
                    acc[i].x = fmaf(ev, wv.x, acc[i].x);
                    acc[i].y = fmaf(ev, wv.y, acc[i].y);
                    acc[i].z = fmaf(ev, wv.z, acc[i].z);
                    acc[i].w = fmaf(ev, wv.w, acc[i].w);
                }
            }
        }

        #pragma unroll
        for (int i = 0; i < 8; ++i) {
            const int v = base + te + 16 * i;
            if (v < NN) {
                float4 o = acc[i];
                o.x = fmaxf(o.x + bv.x, 0.f); o.y = fmaxf(o.y + bv.y, 0.f);
                o.z = fmaxf(o.z + bv.z, 0.f); o.w = fmaxf(o.w + bv.w, 0.f);
                *(float4*)(out + (size_t)v * 64 + c0) = o;
            }
        }
    }
}

// ================= final: LN + MLP + projection (LDS-broadcast GEMMs) =====
__launch_bounds__(256, 2)
__global__ void final_kernel(const float* __restrict__ nodes,
                             const float* __restrict__ gamma,
                             const float* __restrict__ beta,
                             const float* __restrict__ W1, const float* __restrict__ b1,
                             const float* __restrict__ W2, const float* __restrict__ b2,
                             const float* __restrict__ Wp, const float* __restrict__ bp,
                             float* __restrict__ out) {
    __shared__ float w1_lds[64 * 128];
    __shared__ float w2_lds[128 * 64];
    __shared__ float x_lds[16 * 66];
    __shared__ float h_lds[16 * 130];
    const int tid = threadIdx.x;
    for (int i = tid; i < 8192; i += 256) w1_lds[i] = W1[i];
    for (int i = tid; i < 8192; i += 256) w2_lds[i] = W2[i];
    const int r  = tid >> 4;
    const int li = tid & 15;
    const float4 gm4 = *(const float4*)(gamma + li * 4);
    const float4 bt4 = *(const float4*)(beta + li * 4);
    const float4 b1v0 = *(const float4*)(b1 + li * 8);
    const float4 b1v1 = *(const float4*)(b1 + li * 8 + 4);
    const float4 b2v = *(const float4*)(b2 + li * 4);
    const float4 wpv = *(const float4*)(Wp + li * 4);
    const float bp0 = bp[0];

    for (int tile = blockIdx.x; tile < NN / 16; tile += gridDim.x) {
        const int vbase = tile * 16;
        const float4 xv = *(const float4*)(nodes + (size_t)(vbase + r) * 64 + li * 4);
        float s = xv.x + xv.y + xv.z + xv.w;
        #pragma unroll
        for (int off = 1; off < 16; off <<= 1) s += __shfl_xor(s, off, 16);
        const float mu = s * (1.0f / 64.0f);
        const float dx = xv.x - mu, dy = xv.y - mu, dz = xv.z - mu, dw = xv.w - mu;
        float q = dx * dx + dy * dy + dz * dz + dw * dw;
        #pragma unroll
        for (int off = 1; off < 16; off <<= 1) q += __shfl_xor(q, off, 16);
        const float rs = rsqrtf(q * (1.0f / 64.0f) + 1e-5f);
        float* xp = &x_lds[r * 66 + li * 4];
        xp[0] = dx * rs * gm4.x + bt4.x;
        xp[1] = dy * rs * gm4.y + bt4.y;
        xp[2] = dz * rs * gm4.z + bt4.z;
        xp[3] = dw * rs * gm4.w + bt4.w;
        __syncthreads();

        float4 h0 = make_float4(0.f, 0.f, 0.f, 0.f);
        float4 h1 = make_float4(0.f, 0.f, 0.f, 0.f);
        #pragma unroll 8
        for (int k = 0; k < 64; ++k) {
            const float xk = x_lds[r * 66 + k];
            const float4 w0 = *(const float4*)&w1_lds[k * 128 + li * 8];
            const float4 w1v = *(const float4*)&w1_lds[k * 128 + li * 8 + 4];
            h0.x = fmaf(xk, w0.x, h0.x); h0.y = fmaf(xk, w0.y, h0.y);
            h0.z = fmaf(xk, w0.z, h0.z); h0.w = fmaf(xk, w0.w, h0.w);
            h1.x = fmaf(xk, w1v.x, h1.x); h1.y = fmaf(xk, w1v.y, h1.y);
            h1.z = fmaf(xk, w1v.z, h1.z); h1.w = fmaf(xk, w1v.w, h1.w);
        }
        float* hp = &h_lds[r * 130 + li * 8];
        hp[0] = fmaxf(h0.x + b1v0.x, 0.f);
        hp[1] = fmaxf(h0.y + b1v0.y, 0.f);
        hp[2] = fmaxf(h0.z + b1v0.z, 0.f);
        hp[3] = fmaxf(h0.w + b1v0.w, 0.f);
        hp[4] = fmaxf(h1.x + b1v1.x, 0.f);
        hp[5] = fmaxf(h1.y + b1v1.y, 0.f);
        hp[6] = fmaxf(h1.z + b1v1.z, 0.f);
        hp[7] = fmaxf(h1.w + b1v1.w, 0.f);
        __syncthreads();

        float4 o = make_float4(0.f, 0.f, 0.f, 0.f);
        #pragma unroll 8
        for (int k = 0; k < 128; ++k) {
            const float hk = h_lds[r * 130 + k];
            const float4 w = *(const float4*)&w2_lds[k * 64 + li * 4];
            o.x = fmaf(hk, w.x, o.x); o.y = fmaf(hk, w.y, o.y);
            o.z = fmaf(hk, w.z, o.z); o.w = fmaf(hk, w.w, o.w);
        }
        float p = (o.x + b2v.x) * wpv.x + (o.y + b2v.y) * wpv.y +
                  (o.z + b2v.z) * wpv.z + (o.w + b2v.w) * wpv.w;
        #pragma unroll
        for (int off = 1; off < 16; off <<= 1) p += __shfl_xor(p, off, 16);
        if (li == 0) out[vbase + r] = p + bp0;
    }
}

extern "C" void kernel_launch(void* const* d_in, const int* in_sizes, int n_in,
                              void* d_out, int out_size, void* d_ws, size_t ws_size,
                              hipStream_t stream) {
    const float* nodes     = (const float*)d_in[0];
    const float* edges     = (const float*)d_in[1];
    const int*   senders   = (const int*)d_in[2];
    const int*   receivers = (const int*)d_in[3];
    const float* We        = (const float*)d_in[4];
    const float* be        = (const float*)d_in[5];
    const float* Wn        = (const float*)d_in[6];
    const float* bn        = (const float*)d_in[7];
    const float* gamma     = (const float*)d_in[8];
    const float* beta      = (const float*)d_in[9];
    const float* W1        = (const float*)d_in[10];
    const float* b1        = (const float*)d_in[11];
    const float* W2        = (const float*)d_in[12];
    const float* b2        = (const float*)d_in[13];
    const float* Wp        = (const float*)d_in[14];
    const float* bp        = (const float*)d_in[15];
    float* out = (float*)d_out;

    char* ws = (char*)d_ws;
    ushort* ehi      = (ushort*)ws;                          // [NE*64] 102.4 MB (CSR, bf16)
    ushort* Pb       = ehi + (size_t)NE * 64;                // [NN*64] bf16 6.4 MB
    ushort* Qb       = Pb + (size_t)NN * 64;                 // [NN*64] bf16 6.4 MB
    float* nodes_buf = (float*)(Qb + (size_t)NN * 64);       // [NN][64]
    float* aggbuf    = nodes_buf + (size_t)NN * 64;          // [NN][64] raw sums
    int*   cnt_i     = (int*)(aggbuf + (size_t)NN * 64);     // [NN]
    int*   row_start = cnt_i + NN;                           // [NN+1]
    int*   cursor    = row_start + NN + 1;                   // [NN]
    int*   eidx      = cursor + NN;                          // [NE]
    int*   sid       = eidx + NE;                            // [NE]
    int*   rid       = sid + NE;                             // [NE]
    int*   bsum      = rid + NE;                             // [256]
    float* inv       = (float*)(bsum + 256);                 // [NN]
    ushort* WfH      = (ushort*)(inv + NN);                  // [3*4096]
    ushort* WfL      = WfH + 3 * 4096;                       // [3*4096]

    hipMemsetAsync(cnt_i, 0, NN * sizeof(int), stream);
    hipMemsetAsync(cursor, 0, NN * sizeof(int), stream);
    hipMemsetAsync(aggbuf, 0, (size_t)NN * 64 * sizeof(float), stream);  // once; node zeroes after
    hist_kernel<<<(NE + 255) / 256, 256, 0, stream>>>(receivers, cnt_i);
    inv_kernel<<<(NN + 255) / 256, 256, 0, stream>>>(cnt_i, inv);
    scan1_kernel<<<196, 256, 0, stream>>>(cnt_i, row_start, bsum);
    scan2_kernel<<<1, 256, 0, stream>>>(bsum, 196);
    scan3_kernel<<<196, 256, 0, stream>>>(row_start, bsum);
    scatter_kernel<<<(NE + 255) / 256, 256, 0, stream>>>(senders, receivers, row_start,
                                                         cursor, eidx, sid, rid);
    // one-time: We[0:64] -> frag order hi/lo (edge l0 converts edges itself)
    wconv_kernel<<<3, 256, 0, stream>>>(We, WfH, WfL);

    for (int l = 0; l < 3; ++l) {
        const float* ncur = (l == 0) ? nodes : nodes_buf;
        const float* We_l = We + (size_t)l * 192 * 64;
        // [P|Q] = nodes @ [We[64:128] | We[128:192]]  (one A pass, bf16 out)
        gemm_pq_kernel<<<782, 256, 0, stream>>>(ncur, NN, We_l + 64 * 64, We_l + 128 * 64,
                                                Pb, Qb);
        // fused edge GEMM (MFMA) + aggregation (agg pre-zeroed by node/memset)
        edge_mfma_kernel<<<NE / 64, 256, 0, stream>>>(
            (l == 0) ? edges : (const float*)nullptr, ehi,
            (l == 0) ? eidx : (const int*)nullptr,
            WfH + (size_t)l * 4096, WfL + (size_t)l * 4096,
            be + (size_t)l * 64, Pb, Qb, sid, rid, row_start,
            ehi, aggbuf, (l < 2) ? 1 : 0);
        // nodes = relu([nodes | agg*inv] @ Wn + bn); zeroes agg after read
        node_kernel<<<391, 256, 0, stream>>>(ncur, aggbuf, inv,
                                             Wn + (size_t)l * 128 * 64, bn + (size_t)l * 64,
                                             nodes_buf);
    }
    final_kernel<<<625, 256, 0, stream>>>(nodes_buf, gamma, beta,
                                          W1, b1, W2, b2, Wp, bp, out);
}

// Round 16
// 545.137 us; speedup vs baseline: 1.7525x; 1.0522x over previous
//
#include <hip/hip_runtime.h>

#define NN 50000
#define NE 800000

typedef __attribute__((ext_vector_type(8))) short bf16x8;
typedef __attribute__((ext_vector_type(4))) float f32x4;

__device__ __forceinline__ ushort f2bf(float x) {
    union { float f; unsigned u; } v; v.f = x;
    return (ushort)((v.u + 0x7FFF + ((v.u >> 16) & 1)) >> 16);
}
__device__ __forceinline__ float bf2f(ushort b) {
    union { float f; unsigned u; } v; v.u = ((unsigned)b) << 16;
    return v.f;
}
// pack 8 floats -> 8 bf16 in a uint4
__device__ __forceinline__ uint4 pack8(const float* f) {
    ushort hs[8];
    #pragma unroll
    for (int i = 0; i < 8; ++i) hs[i] = f2bf(f[i]);
    uint4 h;
    h.x = (unsigned)hs[0] | ((unsigned)hs[1] << 16);
    h.y = (unsigned)hs[2] | ((unsigned)hs[3] << 16);
    h.z = (unsigned)hs[4] | ((unsigned)hs[5] << 16);
    h.w = (unsigned)hs[6] | ((unsigned)hs[7] << 16);
    return h;
}
// unpack 16 bf16 (2 uint4) -> 16 floats
__device__ __forceinline__ void unpack16(const uint4* p, float* f) {
    const uint4 a = p[0], b = p[1];
    const unsigned u[8] = {a.x, a.y, a.z, a.w, b.x, b.y, b.z, b.w};
    #pragma unroll
    for (int i = 0; i < 8; ++i) {
        f[2 * i]     = bf2f((ushort)(u[i] & 0xffff));
        f[2 * i + 1] = bf2f((ushort)(u[i] >> 16));
    }
}

// ================= CSR build: hist / inv / scan / scatter =================
__global__ void hist_kernel(const int* __restrict__ recv, int* __restrict__ cnt) {
    int i = blockIdx.x * 256 + threadIdx.x;
    if (i < NE) atomicAdd(&cnt[recv[i]], 1);
}

__global__ void inv_kernel(const int* __restrict__ cnt, float* __restrict__ inv) {
    int i = blockIdx.x * 256 + threadIdx.x;
    if (i < NN) inv[i] = 1.0f / (float)max(cnt[i], 1);
}

__global__ void scan1_kernel(const int* __restrict__ cnt, int* __restrict__ excl,
                             int* __restrict__ bsum) {
    const int i = blockIdx.x * 256 + threadIdx.x;
    const int lane = threadIdx.x & 63, wid = threadIdx.x >> 6;
    int orig = (i < NN) ? cnt[i] : 0;
    int x = orig;
    #pragma unroll
    for (int off = 1; off < 64; off <<= 1) {
        int y = __shfl_up(x, off, 64);
        if (lane >= off) x += y;
    }
    __shared__ int ws[4];
    if (lane == 63) ws[wid] = x;
    __syncthreads();
    int add = 0;
    for (int w = 0; w < wid; ++w) add += ws[w];
    x += add;
    if (i < NN) excl[i] = x - orig;
    if (threadIdx.x == 255) bsum[blockIdx.x] = x;
}

__global__ void scan2_kernel(int* __restrict__ bsum, int nb) {
    const int t = threadIdx.x;
    const int lane = t & 63, wid = t >> 6;
    int orig = (t < nb) ? bsum[t] : 0;
    int x = orig;
    #pragma unroll
    for (int off = 1; off < 64; off <<= 1) {
        int y = __shfl_up(x, off, 64);
        if (lane >= off) x += y;
    }
    __shared__ int ws[4];
    if (lane == 63) ws[wid] = x;
    __syncthreads();
    int add = 0;
    for (int w = 0; w < wid; ++w) add += ws[w];
    x += add;
    __syncthreads();
    if (t < nb) bsum[t] = x - orig;
}

__global__ void scan3_kernel(int* __restrict__ excl, const int* __restrict__ bsum) {
    const int i = blockIdx.x * 256 + threadIdx.x;
    if (i < NN) excl[i] += bsum[blockIdx.x];
    if (i == 0) excl[NN] = NE;
}

__global__ void scatter_kernel(const int* __restrict__ senders, const int* __restrict__ recv,
                               const int* __restrict__ row_start,
                               int* __restrict__ cursor, int* __restrict__ eidx,
                               int* __restrict__ sid, int* __restrict__ rid) {
    int i = blockIdx.x * 256 + threadIdx.x;
    if (i < NE) {
        int r = recv[i];
        int p = row_start[r] + atomicAdd(&cursor[r], 1);
        eidx[p] = i;
        sid[p] = senders[i];
        rid[p] = r;
    }
}

// ========== wconv: We[l][0:64] -> MFMA B-fragment order, bf16 hi/lo =======
__global__ void wconv_kernel(const float* __restrict__ We,
                             ushort* __restrict__ WfH, ushort* __restrict__ WfL) {
    const int l = blockIdx.x;
    const float* W = We + (size_t)l * 192 * 64;
    ushort* oh = WfH + (size_t)l * 4096;
    ushort* ol = WfL + (size_t)l * 4096;
    for (int s = threadIdx.x; s < 512; s += 256) {
        const int ktnt = s >> 6, lane = s & 63;
        const int kt = ktnt >> 2, nt = ktnt & 3;
        const int kb = 32 * kt + (lane >> 4) * 8;
        const int c  = 16 * nt + (lane & 15);
        #pragma unroll
        for (int j = 0; j < 8; ++j) {
            const float w = W[(kb + j) * 64 + c];
            const ushort h = f2bf(w);
            oh[s * 8 + j] = h;
            ol[s * 8 + j] = f2bf(w - bf2f(h));
        }
    }
}

// ==== fused P|Q GEMM: [P|Q] = A @ [Wp|Wq], one A pass, bf16 outputs =======
__launch_bounds__(256, 3)
__global__ void gemm_pq_kernel(const float* __restrict__ A, int M,
                               const float* __restrict__ Wp_,  // [64][64]
                               const float* __restrict__ Wq_,  // [64][64]
                               ushort* __restrict__ Pout, ushort* __restrict__ Qout) {
    __shared__ float w_lds[64 * 128];
    __shared__ float e_lds[64 * 68];
    const int tid = threadIdx.x;
    for (int i = tid; i < 8192; i += 256) {
        const int k = i >> 7, c = i & 127;
        w_lds[i] = (c < 64) ? Wp_[k * 64 + c] : Wq_[k * 64 + (c - 64)];
    }
    const int te = tid & 15;
    const int tc = tid >> 4;
    const int srow = tid >> 2, shalf = tid & 3;
    const int ntiles = (M + 63) >> 6;

    for (int t = blockIdx.x; t < ntiles; t += gridDim.x) {
        const int base = t << 6;
        __syncthreads();
        {
            int g = base + srow;
            if (g > M - 1) g = M - 1;
            const float4* src = (const float4*)(A + (size_t)g * 64) + shalf * 4;
            float4* dst = (float4*)&e_lds[srow * 68 + shalf * 16];
            #pragma unroll
            for (int j = 0; j < 4; ++j) dst[j] = src[j];
        }
        __syncthreads();

        float4 acc0[4], acc1[4];
        #pragma unroll
        for (int i = 0; i < 4; ++i) {
            acc0[i] = make_float4(0.f, 0.f, 0.f, 0.f);
            acc1[i] = make_float4(0.f, 0.f, 0.f, 0.f);
        }

        #pragma unroll 2
        for (int kq = 0; kq < 16; ++kq) {
            float evs[4][4];
            #pragma unroll
            for (int i = 0; i < 4; ++i) {
                const float4 q = *(const float4*)&e_lds[(te + 16 * i) * 68 + kq * 4];
                evs[i][0] = q.x; evs[i][1] = q.y; evs[i][2] = q.z; evs[i][3] = q.w;
            }
            #pragma unroll
            for (int j = 0; j < 4; ++j) {
                const float4 w0 = *(const float4*)&w_lds[(kq * 4 + j) * 128 + tc * 8];
                const float4 w1 = *(const float4*)&w_lds[(kq * 4 + j) * 128 + tc * 8 + 4];
                #pragma unroll
                for (int i = 0; i < 4; ++i) {
                    const float ev = evs[i][j];
                    acc0[i].x = fmaf(ev, w0.x, acc0[i].x);
                    acc0[i].y = fmaf(ev, w0.y, acc0[i].y);
                    acc0[i].z = fmaf(ev, w0.z, acc0[i].z);
                    acc0[i].w = fmaf(ev, w0.w, acc0[i].w);
                    acc1[i].x = fmaf(ev, w1.x, acc1[i].x);
                    acc1[i].y = fmaf(ev, w1.y, acc1[i].y);
                    acc1[i].z = fmaf(ev, w1.z, acc1[i].z);
                    acc1[i].w = fmaf(ev, w1.w, acc1[i].w);
                }
            }
        }

        ushort* __restrict__ dstbuf = (tc < 8) ? Pout : Qout;
        const int cd = (tc < 8) ? tc * 8 : (tc - 8) * 8;
        #pragma unroll
        for (int i = 0; i < 4; ++i) {
            const int g = base + te + 16 * i;
            if (g < M) {
                float f[8] = {acc0[i].x, acc0[i].y, acc0[i].z, acc0[i].w,
                              acc1[i].x, acc1[i].y, acc1[i].z, acc1[i].w};
                *((uint4*)dstbuf + ((size_t)g * 8 + cd / 8)) = pack8(f);
            }
        }
    }
}

// ===== CSR-fused edge GEMM (bf16 MFMA) + epilogue + interior-store segsum =
// Round-15 structure; segsum now STORES (no atomic) for nodes whose entire
// edge range lies inside this tile (exactly one block owns them; sum is
// complete) and uses atomics only for the <=2 boundary nodes per tile.
// Values are bit-identical; removes ~80% of atomic RMW traffic.
__launch_bounds__(256, 6)
__global__ void edge_mfma_kernel(const float* __restrict__ efp32,  // l0 input or null
                                 const ushort* ehi,                // l>=1 input (aliases out)
                                 const int* __restrict__ gidx,     // eidx for l0, else null
                                 const ushort* __restrict__ WfH,
                                 const ushort* __restrict__ WfL,
                                 const float* __restrict__ bias,
                                 const ushort* __restrict__ Pb,    // bf16 [NN][64]
                                 const ushort* __restrict__ Qb,    // bf16 [NN][64]
                                 const int* __restrict__ sid,
                                 const int* __restrict__ rid,
                                 const int* __restrict__ row_start,
                                 ushort* out_hi,
                                 float* __restrict__ agg, int write_out) {
    __shared__ ushort a_hi[64 * 64];   // 8 KB, row stride 128 B, XOR-swizzled
    __shared__ float  stash[64 * 68];  // 17.4 KB fp32
    const int tid  = threadIdx.x;
    const int lane = tid & 63;
    const int w    = tid >> 6;
    const int base = blockIdx.x << 6;
    const int rr = tid >> 2, qq = tid & 3;   // linear row/quarter ownership

    // ---- stage: 32 B of bf16 per thread, swizzled LDS store ----
    {
        const int sw = (rr & 7) << 4;
        char* dh = (char*)a_hi + rr * 128;
        if (efp32) {   // l0: gather fp32 row, convert in stage
            const int src = gidx[base + rr];
            const float4* s4 = (const float4*)(efp32 + (size_t)src * 64 + qq * 16);
            float f[16];
            #pragma unroll
            for (int c = 0; c < 4; ++c) {
                const float4 v = s4[c];
                f[c * 4 + 0] = v.x; f[c * 4 + 1] = v.y;
                f[c * 4 + 2] = v.z; f[c * 4 + 3] = v.w;
            }
            *(uint4*)(dh + ((qq * 32) ^ sw))      = pack8(f);
            *(uint4*)(dh + ((qq * 32 + 16) ^ sw)) = pack8(f + 8);
        } else {
            const uint4* sh = (const uint4*)ehi + ((size_t)(base + rr) * 8 + qq * 2);
            const uint4 h0 = sh[0], h1 = sh[1];
            *(uint4*)(dh + ((qq * 32) ^ sw))      = h0;
            *(uint4*)(dh + ((qq * 32 + 16) ^ sw)) = h1;
        }
    }
    __syncthreads();   // tile staged; all input reads done -> in-place safe

    // ---- MFMA: wave w owns rows w*16 .. w*16+15 ----
    f32x4 acc[4];
    #pragma unroll
    for (int nt = 0; nt < 4; ++nt) acc[nt] = (f32x4)0.0f;
    {
        const int rowA = lane & 15, kg = lane >> 4;
        const int arow = w * 16 + rowA;
        const int sw = (rowA & 7) << 4;
        #pragma unroll
        for (int kt = 0; kt < 2; ++kt) {
            const int off = arow * 128 + (((kt * 64) + kg * 16) ^ sw);
            const bf16x8 ah = *(const bf16x8*)((const char*)a_hi + off);
            #pragma unroll
            for (int nt = 0; nt < 4; ++nt) {
                const bf16x8 wH = *(const bf16x8*)(WfH + ((kt * 4 + nt) * 64 + lane) * 8);
                const bf16x8 wL = *(const bf16x8*)(WfL + ((kt * 4 + nt) * 64 + lane) * 8);
                acc[nt] = __builtin_amdgcn_mfma_f32_16x16x32_bf16(ah, wH, acc[nt], 0, 0, 0);
                acc[nt] = __builtin_amdgcn_mfma_f32_16x16x32_bf16(ah, wL, acc[nt], 0, 0, 0);
            }
        }
    }

    // ---- stash RAW gemm results (C-frag layout: col=lane&15, row frag) ----
    {
        const int colC = lane & 15;
        const int rbase = w * 16 + (lane >> 4) * 4;
        #pragma unroll
        for (int j = 0; j < 4; ++j) {
            #pragma unroll
            for (int nt = 0; nt < 4; ++nt)
                stash[(rbase + j) * 68 + 16 * nt + colC] = acc[nt][j];
        }
    }
    __syncthreads();   // raw tile fully in stash

    // ---- linear-row epilogue: bias + P[s] + Q[r] + relu, vectorized ----
    {
        const int e = base + rr;
        const int s_ = sid[e];
        const int r_ = rid[e];
        float* sp = &stash[rr * 68 + qq * 16];
        const float4* bp4 = (const float4*)(bias + qq * 16);
        float pf[16], qf[16];
        unpack16((const uint4*)(Pb + (size_t)s_ * 64 + qq * 16), pf);
        unpack16((const uint4*)(Qb + (size_t)r_ * 64 + qq * 16), qf);
        float f[16];
        #pragma unroll
        for (int c = 0; c < 4; ++c) {
            const float4 sv = *(const float4*)(sp + c * 4);
            const float4 bv = bp4[c];
            f[c * 4 + 0] = fmaxf(sv.x + bv.x + pf[c * 4 + 0] + qf[c * 4 + 0], 0.f);
            f[c * 4 + 1] = fmaxf(sv.y + bv.y + pf[c * 4 + 1] + qf[c * 4 + 1], 0.f);
            f[c * 4 + 2] = fmaxf(sv.z + bv.z + pf[c * 4 + 2] + qf[c * 4 + 2], 0.f);
            f[c * 4 + 3] = fmaxf(sv.w + bv.w + pf[c * 4 + 3] + qf[c * 4 + 3], 0.f);
            *(float4*)(sp + c * 4) = make_float4(f[c * 4 + 0], f[c * 4 + 1],
                                                 f[c * 4 + 2], f[c * 4 + 3]);
        }
        if (write_out) {   // bf16 pack, coalesced linear stores
            uint4* dh = (uint4*)out_hi + ((size_t)e * 8 + qq * 2);
            dh[0] = pack8(f);
            dh[1] = pack8(f + 8);
        }
    }
    __syncthreads();   // final tile fully in stash

    // ---- segment-sum: interior nodes -> plain store; boundary -> atomic ---
    {
        const int v0 = rid[base];
        const int v1 = rid[base + 63];
        const int nv = v1 - v0 + 1;
        for (int idx = tid; idx < nv * 16; idx += 256) {
            const int v  = v0 + (idx >> 4);
            const int cg = (idx & 15) * 4;
            const int rs = row_start[v], re = row_start[v + 1];
            const int lo = rs > base ? rs : base;
            const int hi = re < base + 64 ? re : base + 64;
            if (lo < hi) {
                float4 sum = make_float4(0.f, 0.f, 0.f, 0.f);
                for (int j = lo - base; j < hi - base; ++j) {
                    const float4 ev = *(const float4*)&stash[j * 68 + cg];
                    sum.x += ev.x; sum.y += ev.y; sum.z += ev.z; sum.w += ev.w;
                }
                float* ap = agg + (size_t)v * 64 + cg;
                if (rs >= base && re <= base + 64) {
                    // all of v's edges in this tile: sum complete, sole owner
                    *(float4*)ap = sum;
                } else {
                    atomicAdd(ap + 0, sum.x);
                    atomicAdd(ap + 1, sum.y);
                    atomicAdd(ap + 2, sum.z);
                    atomicAdd(ap + 3, sum.w);
                }
            }
        }
    }
}

// ====== node update: relu([nodes | agg*inv] @ Wn + bn), K=128 =============
// Zeroes agg rows in-place after reading (each row read by exactly one
// block; padding clamp rows skip the zero-write) — removes per-layer memset.
__launch_bounds__(256, 3)
__global__ void node_kernel(const float* __restrict__ nodes_in,
                            float* __restrict__ agg,         // raw sums; zeroed after read
                            const float* __restrict__ inv,   // 1/max(count,1)
                            const float* __restrict__ W,     // [128][64]
                            const float* __restrict__ bias,  // [64]
                            float* __restrict__ out) {
    __shared__ float w_lds[128 * 64];
    __shared__ float e_lds[128 * 33];
    const int tid = threadIdx.x;
    for (int i = tid; i < 8192; i += 256) w_lds[i] = W[i];
    const int te = tid & 15, tc = tid >> 4, c0 = tc * 4;
    const float4 bv = *(const float4*)(bias + c0);
    const int srow = tid >> 1, shalf = tid & 1;
    const int ntiles = (NN + 127) >> 7;

    for (int t = blockIdx.x; t < ntiles; t += gridDim.x) {
        const int base = t << 7;
        float4 acc[8];
        #pragma unroll
        for (int i = 0; i < 8; ++i) acc[i] = make_float4(0.f, 0.f, 0.f, 0.f);

        #pragma unroll
        for (int c = 0; c < 4; ++c) {
            const float* src0 = (c < 2) ? nodes_in : agg;
            const int coff = (c & 1) * 32;
            __syncthreads();
            {
                int g = base + srow;
                if (g > NN - 1) g = NN - 1;
                const float4* src = (const float4*)(src0 + (size_t)g * 64 + coff) + shalf * 4;
                const float scale = (c >= 2) ? inv[g] : 1.0f;
                float* dst = &e_lds[srow * 33 + shalf * 16];
                #pragma unroll
                for (int j = 0; j < 4; ++j) {
                    float4 v = src[j];
                    dst[j * 4 + 0] = v.x * scale; dst[j * 4 + 1] = v.y * scale;
                    dst[j * 4 + 2] = v.z * scale; dst[j * 4 + 3] = v.w * scale;
                }
                if (c >= 2 && base + srow < NN) {   // zero after read (own row only)
                    float4* wz = (float4*)(agg + (size_t)g * 64 + coff) + shalf * 4;
                    const float4 z = make_float4(0.f, 0.f, 0.f, 0.f);
                    #pragma unroll
                    for (int j = 0; j < 4; ++j) wz[j] = z;
                }
            }
            __syncthreads();
            #pragma unroll 4
            for (int k = 0; k < 32; ++k) {
                const float4 wv = *(const float4*)&w_lds[(c * 32 + k) * 64 + c0];
                #pragma unroll
                for (int i = 0; i < 8; ++i) {
                    const float ev = e_lds[(te + 16 * i) * 33 + k];
                    acc[i].x = fmaf(ev, wv.x, acc[i].x);
                    acc[i].y = fmaf(ev, wv.y, acc[i].y);
                    acc[i].z = fmaf(ev, wv.z, acc[i].z);
                    acc[i].w = fmaf(ev, wv.w, acc[i].w);
                }
            }
        }

        #pragma unroll
        for (int i = 0; i < 8; ++i) {
            const int v = base + te + 16 * i;
            if (v < NN) {
                float4 o = acc[i];
                o.x = fmaxf(o.x + bv.x, 0.f); o.y = fmaxf(o.y + bv.y, 0.f);
                o.z = fmaxf(o.z + bv.z, 0.f); o.w = fmaxf(o.w + bv.w, 0.f);
                *(float4*)(out + (size_t)v * 64 + c0) = o;
            }
        }
    }
}

// ================= final: LN + MLP + projection (LDS-broadcast GEMMs) =====
__launch_bounds__(256, 2)
__global__ void final_kernel(const float* __restrict__ nodes,
                             const float* __restrict__ gamma,
                             const float* __restrict__ beta,
                             const float* __restrict__ W1, const float* __restrict__ b1,
                             const float* __restrict__ W2, const float* __restrict__ b2,
                             const float* __restrict__ Wp, const float* __restrict__ bp,
                             float* __restrict__ out) {
    __shared__ float w1_lds[64 * 128];
    __shared__ float w2_lds[128 * 64];
    __shared__ float x_lds[16 * 66];
    __shared__ float h_lds[16 * 130];
    const int tid = threadIdx.x;
    for (int i = tid; i < 8192; i += 256) w1_lds[i] = W1[i];
    for (int i = tid; i < 8192; i += 256) w2_lds[i] = W2[i];
    const int r  = tid >> 4;
    const int li = tid & 15;
    const float4 gm4 = *(const float4*)(gamma + li * 4);
    const float4 bt4 = *(const float4*)(beta + li * 4);
    const float4 b1v0 = *(const float4*)(b1 + li * 8);
    const float4 b1v1 = *(const float4*)(b1 + li * 8 + 4);
    const float4 b2v = *(const float4*)(b2 + li * 4);
    const float4 wpv = *(const float4*)(Wp + li * 4);
    const float bp0 = bp[0];

    for (int tile = blockIdx.x; tile < NN / 16; tile += gridDim.x) {
        const int vbase = tile * 16;
        const float4 xv = *(const float4*)(nodes + (size_t)(vbase + r) * 64 + li * 4);
        float s = xv.x + xv.y + xv.z + xv.w;
        #pragma unroll
        for (int off = 1; off < 16; off <<= 1) s += __shfl_xor(s, off, 16);
        const float mu = s * (1.0f / 64.0f);
        const float dx = xv.x - mu, dy = xv.y - mu, dz = xv.z - mu, dw = xv.w - mu;
        float q = dx * dx + dy * dy + dz * dz + dw * dw;
        #pragma unroll
        for (int off = 1; off < 16; off <<= 1) q += __shfl_xor(q, off, 16);
        const float rs = rsqrtf(q * (1.0f / 64.0f) + 1e-5f);
        float* xp = &x_lds[r * 66 + li * 4];
        xp[0] = dx * rs * gm4.x + bt4.x;
        xp[1] = dy * rs * gm4.y + bt4.y;
        xp[2] = dz * rs * gm4.z + bt4.z;
        xp[3] = dw * rs * gm4.w + bt4.w;
        __syncthreads();

        float4 h0 = make_float4(0.f, 0.f, 0.f, 0.f);
        float4 h1 = make_float4(0.f, 0.f, 0.f, 0.f);
        #pragma unroll 8
        for (int k = 0; k < 64; ++k) {
            const float xk = x_lds[r * 66 + k];
            const float4 w0 = *(const float4*)&w1_lds[k * 128 + li * 8];
            const float4 w1v = *(const float4*)&w1_lds[k * 128 + li * 8 + 4];
            h0.x = fmaf(xk, w0.x, h0.x); h0.y = fmaf(xk, w0.y, h0.y);
            h0.z = fmaf(xk, w0.z, h0.z); h0.w = fmaf(xk, w0.w, h0.w);
            h1.x = fmaf(xk, w1v.x, h1.x); h1.y = fmaf(xk, w1v.y, h1.y);
            h1.z = fmaf(xk, w1v.z, h1.z); h1.w = fmaf(xk, w1v.w, h1.w);
        }
        float* hp = &h_lds[r * 130 + li * 8];
        hp[0] = fmaxf(h0.x + b1v0.x, 0.f);
        hp[1] = fmaxf(h0.y + b1v0.y, 0.f);
        hp[2] = fmaxf(h0.z + b1v0.z, 0.f);
        hp[3] = fmaxf(h0.w + b1v0.w, 0.f);
        hp[4] = fmaxf(h1.x + b1v1.x, 0.f);
        hp[5] = fmaxf(h1.y + b1v1.y, 0.f);
        hp[6] = fmaxf(h1.z + b1v1.z, 0.f);
        hp[7] = fmaxf(h1.w + b1v1.w, 0.f);
        __syncthreads();

        float4 o = make_float4(0.f, 0.f, 0.f, 0.f);
        #pragma unroll 8
        for (int k = 0; k < 128; ++k) {
            const float hk = h_lds[r * 130 + k];
            const float4 w = *(const float4*)&w2_lds[k * 64 + li * 4];
            o.x = fmaf(hk, w.x, o.x); o.y = fmaf(hk, w.y, o.y);
            o.z = fmaf(hk, w.z, o.z); o.w = fmaf(hk, w.w, o.w);
        }
        float p = (o.x + b2v.x) * wpv.x + (o.y + b2v.y) * wpv.y +
                  (o.z + b2v.z) * wpv.z + (o.w + b2v.w) * wpv.w;
        #pragma unroll
        for (int off = 1; off < 16; off <<= 1) p += __shfl_xor(p, off, 16);
        if (li == 0) out[vbase + r] = p + bp0;
    }
}

extern "C" void kernel_launch(void* const* d_in, const int* in_sizes, int n_in,
                              void* d_out, int out_size, void* d_ws, size_t ws_size,
                              hipStream_t stream) {
    const float* nodes     = (const float*)d_in[0];
    const float* edges     = (const float*)d_in[1];
    const int*   senders   = (const int*)d_in[2];
    const int*   receivers = (const int*)d_in[3];
    const float* We        = (const float*)d_in[4];
    const float* be        = (const float*)d_in[5];
    const float* Wn        = (const float*)d_in[6];
    const float* bn        = (const float*)d_in[7];
    const float* gamma     = (const float*)d_in[8];
    const float* beta      = (const float*)d_in[9];
    const float* W1        = (const float*)d_in[10];
    const float* b1        = (const float*)d_in[11];
    const float* W2        = (const float*)d_in[12];
    const float* b2        = (const float*)d_in[13];
    const float* Wp        = (const float*)d_in[14];
    const float* bp        = (const float*)d_in[15];
    float* out = (float*)d_out;

    char* ws = (char*)d_ws;
    ushort* ehi      = (ushort*)ws;                          // [NE*64] 102.4 MB (CSR, bf16)
    ushort* Pb       = ehi + (size_t)NE * 64;                // [NN*64] bf16 6.4 MB
    ushort* Qb       = Pb + (size_t)NN * 64;                 // [NN*64] bf16 6.4 MB
    float* nodes_buf = (float*)(Qb + (size_t)NN * 64);       // [NN][64]
    float* aggbuf    = nodes_buf + (size_t)NN * 64;          // [NN][64] raw sums
    int*   cnt_i     = (int*)(aggbuf + (size_t)NN * 64);     // [NN]
    int*   row_start = cnt_i + NN;                           // [NN+1]
    int*   cursor    = row_start + NN + 1;                   // [NN]
    int*   eidx      = cursor + NN;                          // [NE]
    int*   sid       = eidx + NE;                            // [NE]
    int*   rid       = sid + NE;                             // [NE]
    int*   bsum      = rid + NE;                             // [256]
    float* inv       = (float*)(bsum + 256);                 // [NN]
    ushort* WfH      = (ushort*)(inv + NN);                  // [3*4096]
    ushort* WfL      = WfH + 3 * 4096;                       // [3*4096]

    hipMemsetAsync(cnt_i, 0, NN * sizeof(int), stream);
    hipMemsetAsync(cursor, 0, NN * sizeof(int), stream);
    hipMemsetAsync(aggbuf, 0, (size_t)NN * 64 * sizeof(float), stream);  // once; node zeroes after
    hist_kernel<<<(NE + 255) / 256, 256, 0, stream>>>(receivers, cnt_i);
    inv_kernel<<<(NN + 255) / 256, 256, 0, stream>>>(cnt_i, inv);
    scan1_kernel<<<196, 256, 0, stream>>>(cnt_i, row_start, bsum);
    scan2_kernel<<<1, 256, 0, stream>>>(bsum, 196);
    scan3_kernel<<<196, 256, 0, stream>>>(row_start, bsum);
    scatter_kernel<<<(NE + 255) / 256, 256, 0, stream>>>(senders, receivers, row_start,
                                                         cursor, eidx, sid, rid);
    // one-time: We[0:64] -> frag order hi/lo (edge l0 converts edges itself)
    wconv_kernel<<<3, 256, 0, stream>>>(We, WfH, WfL);

    for (int l = 0; l < 3; ++l) {
        const float* ncur = (l == 0) ? nodes : nodes_buf;
        const float* We_l = We + (size_t)l * 192 * 64;
        // [P|Q] = nodes @ [We[64:128] | We[128:192]]  (one A pass, bf16 out)
        gemm_pq_kernel<<<782, 256, 0, stream>>>(ncur, NN, We_l + 64 * 64, We_l + 128 * 64,
                                                Pb, Qb);
        // fused edge GEMM (MFMA) + aggregation (agg pre-zeroed by node/memset)
        edge_mfma_kernel<<<NE / 64, 256, 0, stream>>>(
            (l == 0) ? edges : (const float*)nullptr, ehi,
            (l == 0) ? eidx : (const int*)nullptr,
            WfH + (size_t)l * 4096, WfL + (size_t)l * 4096,
            be + (size_t)l * 64, Pb, Qb, sid, rid, row_start,
            ehi, aggbuf, (l < 2) ? 1 : 0);
        // nodes = relu([nodes | agg*inv] @ Wn + bn); zeroes agg after read
        node_kernel<<<391, 256, 0, stream>>>(ncur, aggbuf, inv,
                                             Wn + (size_t)l * 128 * 64, bn + (size_t)l * 64,
                                             nodes_buf);
    }
    final_kernel<<<625, 256, 0, stream>>>(nodes_buf, gamma, beta,
                                          W1, b1, W2, b2, Wp, bp, out);
}